// Round 1
// baseline (4005.912 us; speedup 1.0000x reference)
//
#include <hip/hip_runtime.h>
#include <stdint.h>

#define BB      128
#define DIN     512
#define DMODEL  2048
#define MEMN    25
#define NSY     256
#define OUTD    1000
#define ITERS   24
#define SYNCN   32896
#define KPAD    33280      // padded K for out gemm (26*1280, each chunk = 40*32)
#define NPAD    1024
#define NSPLIT  26
#define KCH     1280
#define PREDTOT (BB*OUTD*ITERS)

typedef __attribute__((ext_vector_type(8))) short bf16x8;
typedef __attribute__((ext_vector_type(4))) float f32x4;

__device__ __forceinline__ unsigned short f2bf(float x){
    unsigned int u = __float_as_uint(x);
    u += 0x7fffu + ((u >> 16) & 1u);
    return (unsigned short)(u >> 16);
}
__device__ __forceinline__ float sigm(float x){ return 1.f/(1.f + __expf(-x)); }

// ---------------- init kernels (run every launch: ws is re-poisoned) ----------------

// trace layout: [m][d][b]  (b fastest)
__global__ __launch_bounds__(256) void init_trace_k(const float* __restrict__ st, float* __restrict__ trace){
    const long N = (long)MEMN*DMODEL*BB;
    for (long i = (long)blockIdx.x*256 + threadIdx.x; i < N; i += (long)gridDim.x*256){
        int m = (int)(i / (DMODEL*BB));
        int rem = (int)(i % (DMODEL*BB));
        int d = rem >> 7;
        trace[i] = st[d*MEMN + m];
    }
}

// act layout: [d][b]
__global__ __launch_bounds__(256) void init_act_k(const float* __restrict__ sas, float* __restrict__ act){
    for (int i = blockIdx.x*256 + threadIdx.x; i < DMODEL*BB; i += gridDim.x*256)
        act[i] = sas[i >> 7];
}

__global__ __launch_bounds__(256) void init_alpha_beta_k(const float* __restrict__ sas,
    const int* __restrict__ il, const int* __restrict__ ir,
    float* __restrict__ alpha, float* __restrict__ beta){
    int i = blockIdx.x, tid = threadIdx.x;
    if (tid >= NSY - i) return;
    int j = i + tid;
    int k = i*(2*NSY - i + 1)/2 + tid;
    float a0 = sas[il[i]] * sas[ir[j]];
    beta[k] = 1.f;
    for (int b = 0; b < BB; ++b) alpha[b*SYNCN + k] = a0;
}

// generic f32 transpose: in[R][C] -> out[C][R]
__global__ __launch_bounds__(256) void transpose_f32_k(const float* __restrict__ in, float* __restrict__ out, int R, int C){
    __shared__ float S[64][65];
    int r0 = blockIdx.y*64, c0 = blockIdx.x*64;
    for (int i = threadIdx.x; i < 64*64; i += 256){
        int rr = i >> 6, cc = i & 63;
        int r = r0+rr, c = c0+cc;
        if (r < R && c < C) S[rr][cc] = in[(long)r*C + c];
    }
    __syncthreads();
    for (int i = threadIdx.x; i < 64*64; i += 256){
        int cc = i >> 6, rr = i & 63;
        int r = r0+rr, c = c0+cc;
        if (r < R && c < C) out[(long)c*R + r] = S[rr][cc];
    }
}

// out_w f32 [SYNCN][OUTD] -> bf16 [NPAD][KPAD] (transposed, zero-padded)
__global__ __launch_bounds__(256) void wbf_transpose_k(const float* __restrict__ w, unsigned short* __restrict__ wt){
    __shared__ float S[64][65];
    int k0 = blockIdx.x*64, n0 = blockIdx.y*64;
    for (int i = threadIdx.x; i < 64*64; i += 256){
        int kk = i >> 6, cc = i & 63;
        int k = k0+kk, n = n0+cc;
        float v = 0.f;
        if (k < SYNCN && n < OUTD) v = w[(long)k*OUTD + n];
        S[kk][cc] = v;
    }
    __syncthreads();
    for (int i = threadIdx.x; i < 64*64; i += 256){
        int nn = i >> 6, kk = i & 63;
        wt[(long)(n0+nn)*KPAD + (k0+kk)] = f2bf(S[kk][nn]);
    }
}

__global__ __launch_bounds__(256) void sync_pad_k(unsigned short* __restrict__ syncb){
    int b = blockIdx.x;
    for (int k = SYNCN + threadIdx.x; k < KPAD; k += 256) syncb[(long)b*KPAD + k] = 0;
}

// ---------------- per-iteration kernels ----------------

// fp32 GEMM: out[b][j](4096 cols) = (bias?) + sum_k A[a0+k][b] * Bw[(browbase + s*512 + k)][j], K=512 per s
// A layout [k][128], Bw = syn_w [2560][4096]
__global__ __launch_bounds__(256) void gemm_syn_k(const float* __restrict__ A, const float* __restrict__ Bw,
    const float* __restrict__ bias, float* __restrict__ out, int browbase, int outStrideS){
    int s = blockIdx.y;
    int j_base = blockIdx.x*64;
    int tid = threadIdx.x;
    A  += (long)s*512*BB;
    Bw += (long)(browbase + s*512)*4096;
    out += (long)s*outStrideS;

    __shared__ float As[16][128];
    __shared__ float Bs[16][68];

    int bg = tid & 15, jg = tid >> 4;
    int b0 = bg*8, j0 = jg*4;
    float acc[8][4];
#pragma unroll
    for (int i = 0; i < 8; ++i)
#pragma unroll
        for (int q = 0; q < 4; ++q) acc[i][q] = 0.f;

    for (int kt = 0; kt < 32; ++kt){
        {
            int i0 = tid*8;
            int kk = i0 >> 7, bb = i0 & 127;
            const float4* src = (const float4*)(A + (long)(kt*16+kk)*BB + bb);
            float4 v0 = src[0], v1 = src[1];
            *(float4*)&As[kk][bb]   = v0;
            *(float4*)&As[kk][bb+4] = v1;
        }
        {
            int i0 = tid*4;
            int kk = i0 >> 6, jj = i0 & 63;
            float4 v = *(const float4*)(Bw + (long)(kt*16+kk)*4096 + j_base + jj);
            *(float4*)&Bs[kk][jj] = v;
        }
        __syncthreads();
#pragma unroll
        for (int kk = 0; kk < 16; ++kk){
            float a[8], bv[4];
            *(float4*)&a[0] = *(float4*)&As[kk][b0];
            *(float4*)&a[4] = *(float4*)&As[kk][b0+4];
            *(float4*)&bv[0] = *(float4*)&Bs[kk][j0];
#pragma unroll
            for (int i = 0; i < 8; ++i)
#pragma unroll
                for (int q = 0; q < 4; ++q) acc[i][q] += a[i]*bv[q];
        }
        __syncthreads();
    }
#pragma unroll
    for (int i = 0; i < 8; ++i){
        int bb = b0 + i;
        float4 v;
        v.x = acc[i][0]; v.y = acc[i][1]; v.z = acc[i][2]; v.w = acc[i][3];
        if (bias){
            v.x += bias[j_base+j0+0]; v.y += bias[j_base+j0+1];
            v.z += bias[j_base+j0+2]; v.w += bias[j_base+j0+3];
        }
        *(float4*)(out + (long)bb*4096 + j_base + j0) = v;
    }
}

// GLU + LayerNorm; z = C0 + sum_s zpart[s]; writes state into trace[slot][d][b]
__global__ __launch_bounds__(256) void glu_ln_k(const float* __restrict__ C0, const float* __restrict__ zp,
    const float* __restrict__ lng, const float* __restrict__ lnb, float* __restrict__ trace, int slot){
    int b = blockIdx.x, tid = threadIdx.x;
    __shared__ float sbuf[DMODEL];
    __shared__ float red1[256], red2[256];
    float s1 = 0.f, s2 = 0.f;
#pragma unroll
    for (int q = 0; q < 8; ++q){
        int d = tid + q*256;
        float a = C0[(long)b*4096 + d];
        float g = C0[(long)b*4096 + 2048 + d];
#pragma unroll
        for (int s = 0; s < 4; ++s){
            a += zp[(long)s*524288 + (long)b*4096 + d];
            g += zp[(long)s*524288 + (long)b*4096 + 2048 + d];
        }
        float sv = a * sigm(g);
        sbuf[d] = sv;
        s1 += sv; s2 += sv*sv;
    }
    red1[tid] = s1; red2[tid] = s2; __syncthreads();
    for (int o = 128; o; o >>= 1){
        if (tid < o){ red1[tid] += red1[tid+o]; red2[tid] += red2[tid+o]; }
        __syncthreads();
    }
    float mu = red1[0]*(1.f/2048.f);
    float var = red2[0]*(1.f/2048.f) - mu*mu;
    float inv = rsqrtf(var + 1e-5f);
#pragma unroll
    for (int q = 0; q < 8; ++q){
        int d = tid + q*256;
        float st = (sbuf[d]-mu)*inv*lng[d] + lnb[d];
        trace[(long)slot*(DMODEL*BB) + (long)d*BB + b] = st;
    }
}

// trace_proc: per-d block. h=glu(T@W1+b1) (128x64), o=glu(hh@W2+b2), act=o0
__global__ __launch_bounds__(256) void trace_proc_k(const float* __restrict__ trace, const float* __restrict__ w1t,
    const float* __restrict__ b1, const float* __restrict__ w2t, const float* __restrict__ b2,
    float* __restrict__ act, int t){
    int d = blockIdx.x, tid = threadIdx.x;
    __shared__ float T[MEMN*128];
    __shared__ float W1[MEMN*64];
    __shared__ float hh[128*33];
    __shared__ float w2s[64];
    for (int i = tid; i < MEMN*128; i += 256){
        int m = i >> 7, bb = i & 127;
        int phys = (t + 1 + m) % MEMN;
        T[i] = trace[(long)phys*(DMODEL*BB) + (long)d*BB + bb];
    }
    for (int i = tid; i < 1600; i += 256) W1[i] = w1t[(long)d*1600 + i];
    if (tid < 64) w2s[tid] = w2t[(long)d*64 + tid];
    __syncthreads();

    int bg = tid & 31, jg = tid >> 5;
    int b0 = bg*4, jl = jg*4, jh = jl + 32;
    float accA[4][4], accG[4][4];
    float biasA[4], biasG[4];
#pragma unroll
    for (int q = 0; q < 4; ++q){
        biasA[q] = b1[(long)d*64 + jl + q];
        biasG[q] = b1[(long)d*64 + jh + q];
    }
#pragma unroll
    for (int i = 0; i < 4; ++i)
#pragma unroll
        for (int q = 0; q < 4; ++q){ accA[i][q] = 0.f; accG[i][q] = 0.f; }

    for (int m = 0; m < MEMN; ++m){
        float tv[4], wa[4], wg[4];
        *(float4*)tv = *(float4*)&T[m*128 + b0];
        *(float4*)wa = *(float4*)&W1[m*64 + jl];
        *(float4*)wg = *(float4*)&W1[m*64 + jh];
#pragma unroll
        for (int i = 0; i < 4; ++i)
#pragma unroll
            for (int q = 0; q < 4; ++q){
                accA[i][q] += tv[i]*wa[q];
                accG[i][q] += tv[i]*wg[q];
            }
    }
#pragma unroll
    for (int i = 0; i < 4; ++i)
#pragma unroll
        for (int q = 0; q < 4; ++q){
            float hv = (accA[i][q]+biasA[q]) * sigm(accG[i][q]+biasG[q]);
            hh[(b0+i)*33 + jl + q] = hv;
        }
    __syncthreads();
    if (tid < 128){
        int bb = tid;
        float o0 = b2[(long)d*2+0], o1 = b2[(long)d*2+1];
#pragma unroll
        for (int h = 0; h < 32; ++h){
            float hv = hh[bb*33 + h];
            o0 += hv * w2s[h*2+0];
            o1 += hv * w2s[h*2+1];
        }
        act[(long)d*BB + bb] = o0 * sigm(o1);
    }
}

// pairwise + alpha/beta update + sync (bf16). block = row i; lane j-i.
__global__ __launch_bounds__(256) void pairwise_sync_k(const float* __restrict__ act, const float* __restrict__ decay,
    const int* __restrict__ il, const int* __restrict__ ir,
    float* __restrict__ alpha, float* __restrict__ beta, unsigned short* __restrict__ syncb){
    int i = blockIdx.x, tid = threadIdx.x;
    if (tid >= NSY - i) return;
    int j = i + tid;
    int k = i*(2*NSY - i + 1)/2 + tid;
    float r = __expf(-fminf(fmaxf(decay[k], 0.f), 15.f));
    float bet = r*beta[k] + 1.f;
    beta[k] = bet;
    float rs = rsqrtf(bet);
    const float* aL = act + (long)il[i]*BB;
    const float* aR = act + (long)ir[j]*BB;
    for (int b = 0; b < BB; ++b){
        float pp = aL[b]*aR[b];
        float al = r*alpha[(long)b*SYNCN + k] + pp;
        alpha[(long)b*SYNCN + k] = al;
        syncb[(long)b*KPAD + k] = f2bf(al*rs);
    }
}

// bf16 MFMA split-K GEMM: part[sk][128][NPAD] = sync[128][KPAD-chunk] @ w_t^T
__global__ __launch_bounds__(256) void out_gemm_k(const unsigned short* __restrict__ Abf,
    const unsigned short* __restrict__ Bbf, float* __restrict__ part){
    int n_base = blockIdx.x*128;
    int sk = blockIdx.y;
    int tid = threadIdx.x;
    int wid = tid >> 6, lane = tid & 63;
    int wm = (wid & 1)*64, wn = (wid >> 1)*64;
    long k_base = (long)sk*KCH;
    __shared__ unsigned short As[128*40];
    __shared__ unsigned short Bs[128*40];
    f32x4 c[4][4];
#pragma unroll
    for (int a = 0; a < 4; ++a)
#pragma unroll
        for (int b = 0; b < 4; ++b) c[a][b] = (f32x4){0.f,0.f,0.f,0.f};

    int mrow = lane & 15, kq = lane >> 4;
    for (int ks = 0; ks < 40; ++ks){
#pragma unroll
        for (int p = 0; p < 2; ++p){
            int i = tid*2 + p;             // 0..511
            int row = i >> 2, seg = i & 3;
            long koff = k_base + ks*32 + seg*8;
            uint4 va = *(const uint4*)(Abf + (long)row*KPAD + koff);
            *(uint4*)&As[row*40 + seg*8] = va;
            uint4 vb = *(const uint4*)(Bbf + (long)(n_base+row)*KPAD + koff);
            *(uint4*)&Bs[row*40 + seg*8] = vb;
        }
        __syncthreads();
        bf16x8 af[4], bf[4];
#pragma unroll
        for (int x = 0; x < 4; ++x){
            af[x] = *(const bf16x8*)&As[(wm + x*16 + mrow)*40 + kq*8];
            bf[x] = *(const bf16x8*)&Bs[(wn + x*16 + mrow)*40 + kq*8];
        }
#pragma unroll
        for (int a = 0; a < 4; ++a)
#pragma unroll
            for (int b = 0; b < 4; ++b)
                c[a][b] = __builtin_amdgcn_mfma_f32_16x16x32_bf16(af[a], bf[b], c[a][b], 0, 0, 0);
        __syncthreads();
    }
    float* outp = part + (long)sk*(128*NPAD);
#pragma unroll
    for (int a = 0; a < 4; ++a)
#pragma unroll
        for (int b = 0; b < 4; ++b){
            int r0 = wm + a*16 + (lane >> 4)*4;
            int col = n_base + wn + b*16 + (lane & 15);
#pragma unroll
            for (int reg = 0; reg < 4; ++reg)
                outp[(long)(r0+reg)*NPAD + col] = c[a][b][reg];
        }
}

// reduce split-K partials + bias, entropy, write pred_all[t][b][n] and certainties
__global__ __launch_bounds__(256) void reduce_softmax_k(const float* __restrict__ part, const float* __restrict__ outb,
    float* __restrict__ pred_all, float* __restrict__ dout, int t){
    int b = blockIdx.x, tid = threadIdx.x;
    __shared__ float red[256];
    float v[4];
    float lmax = -1e30f;
#pragma unroll
    for (int q = 0; q < 4; ++q){
        int n = tid + q*256;
        float s = -1e30f;
        if (n < OUTD){
            s = outb[n];
            for (int sk = 0; sk < NSPLIT; ++sk) s += part[(long)sk*(128*NPAD) + (long)b*NPAD + n];
        }
        v[q] = s;
        lmax = fmaxf(lmax, s);
    }
    red[tid] = lmax; __syncthreads();
    for (int o = 128; o; o >>= 1){ if (tid < o) red[tid] = fmaxf(red[tid], red[tid+o]); __syncthreads(); }
    float M = red[0]; __syncthreads();
    float z = 0.f, sv = 0.f;
#pragma unroll
    for (int q = 0; q < 4; ++q){
        int n = tid + q*256;
        if (n < OUTD){
            float e = __expf(v[q]-M);
            z += e; sv += e*v[q];
        }
    }
    red[tid] = z; __syncthreads();
    for (int o = 128; o; o >>= 1){ if (tid < o) red[tid] += red[tid+o]; __syncthreads(); }
    float Z = red[0]; __syncthreads();
    red[tid] = sv; __syncthreads();
    for (int o = 128; o; o >>= 1){ if (tid < o) red[tid] += red[tid+o]; __syncthreads(); }
    float S = red[0];
    if (tid == 0){
        float logZ = M + __logf(Z);
        float ne = (logZ - S/Z) / 6.907755278982137f;
        dout[PREDTOT + b*48 + t] = ne;
        dout[PREDTOT + b*48 + 24 + t] = 1.f - ne;
    }
#pragma unroll
    for (int q = 0; q < 4; ++q){
        int n = tid + q*256;
        if (n < OUTD) pred_all[(long)t*(BB*OUTD) + (long)b*OUTD + n] = v[q];
    }
}

// pred_all [t][b][n] -> d_out [b][n][t]
__global__ __launch_bounds__(256) void transpose_pred_k(const float* __restrict__ pa, float* __restrict__ dout){
    int b = blockIdx.x;
    int n0 = blockIdx.y*64;
    __shared__ float S[64][25];
    for (int i = threadIdx.x; i < 24*64; i += 256){
        int tt = i >> 6, j = i & 63;
        int n = n0 + j;
        if (n < OUTD) S[j][tt] = pa[(long)tt*(BB*OUTD) + (long)b*OUTD + n];
    }
    __syncthreads();
    for (int i = threadIdx.x; i < 64*24; i += 256){
        int j = i / 24, tt = i % 24;
        int n = n0 + j;
        if (n < OUTD) dout[(long)b*(OUTD*ITERS) + (long)n*ITERS + tt] = S[j][tt];
    }
}

// ---------------- host ----------------

extern "C" void kernel_launch(void* const* d_in, const int* in_sizes, int n_in,
                              void* d_out, int out_size, void* d_ws, size_t ws_size,
                              hipStream_t stream){
    const float* x      = (const float*)d_in[0];
    const float* syn_w  = (const float*)d_in[1];
    const float* syn_b  = (const float*)d_in[2];
    const float* ln_g   = (const float*)d_in[3];
    const float* ln_b   = (const float*)d_in[4];
    const float* tp_w1  = (const float*)d_in[5];
    const float* tp_b1  = (const float*)d_in[6];
    const float* tp_w2  = (const float*)d_in[7];
    const float* tp_b2  = (const float*)d_in[8];
    const float* sas    = (const float*)d_in[9];
    const float* strc   = (const float*)d_in[10];
    const float* decay  = (const float*)d_in[11];
    const float* out_w  = (const float*)d_in[12];
    const float* out_b  = (const float*)d_in[13];
    const int*   il     = (const int*)d_in[14];
    const int*   ir     = (const int*)d_in[15];
    float* dout = (float*)d_out;

    char* ws = (char*)d_ws;
    size_t off = 0;
    auto alloc = [&](size_t bytes)->void*{
        void* p = ws + off;
        off += (bytes + 255) & ~(size_t)255;
        return p;
    };
    float* trace   = (float*)alloc((size_t)MEMN*DMODEL*BB*4);     // 26.2 MB  [m][d][b]
    float* act     = (float*)alloc((size_t)DMODEL*BB*4);          // 1 MB     [d][b]
    float* C0      = (float*)alloc((size_t)BB*4096*4);            // 2.1 MB
    float* zpart   = (float*)alloc((size_t)4*BB*4096*4);          // 8.4 MB
    float* xt      = (float*)alloc((size_t)DIN*BB*4);             // 0.26 MB  [k][b]
    float* w1t     = (float*)alloc((size_t)DMODEL*1600*4);        // 13.1 MB  [d][m*64+j]
    float* w2t     = (float*)alloc((size_t)DMODEL*64*4);          // 0.52 MB  [d][h*2+o]
    float* alpha   = (float*)alloc((size_t)BB*SYNCN*4);           // 16.8 MB
    float* beta    = (float*)alloc((size_t)SYNCN*4);              // 0.13 MB
    unsigned short* syncb = (unsigned short*)alloc((size_t)BB*KPAD*2);   // 8.5 MB  [b][k]
    unsigned short* wbt   = (unsigned short*)alloc((size_t)NPAD*KPAD*2); // 68.2 MB [n][k]
    float* part    = (float*)alloc((size_t)NSPLIT*BB*NPAD*4);     // 13.6 MB
    float* pred_all= (float*)alloc((size_t)ITERS*BB*OUTD*4);      // 12.3 MB
    (void)ws_size; (void)in_sizes; (void)n_in; (void)out_size;

    // ---- once-per-launch precompute ----
    init_trace_k<<<8192, 256, 0, stream>>>(strc, trace);
    init_act_k<<<1024, 256, 0, stream>>>(sas, act);
    init_alpha_beta_k<<<256, 256, 0, stream>>>(sas, il, ir, alpha, beta);
    transpose_f32_k<<<dim3(32, 25), 256, 0, stream>>>(tp_w1, w1t, 1600, 2048);
    transpose_f32_k<<<dim3(32, 1),  256, 0, stream>>>(tp_w2, w2t, 64, 2048);
    transpose_f32_k<<<dim3(8, 2),   256, 0, stream>>>(x, xt, 128, 512);
    wbf_transpose_k<<<dim3(520, 16), 256, 0, stream>>>(out_w, wbt);
    sync_pad_k<<<128, 256, 0, stream>>>(syncb);
    // C0 = syn_b + x @ syn_w[0:512]
    gemm_syn_k<<<dim3(64, 1), 256, 0, stream>>>(xt, syn_w, syn_b, C0, 0, 0);

    // ---- 24 sequential iterations ----
    for (int t = 0; t < ITERS; ++t){
        gemm_syn_k<<<dim3(64, 4), 256, 0, stream>>>(act, syn_w, nullptr, zpart, 512, BB*4096);
        glu_ln_k<<<128, 256, 0, stream>>>(C0, zpart, ln_g, ln_b, trace, t % MEMN);
        trace_proc_k<<<2048, 256, 0, stream>>>(trace, w1t, tp_b1, w2t, tp_b2, act, t);
        pairwise_sync_k<<<256, 256, 0, stream>>>(act, decay, il, ir, alpha, beta, syncb);
        out_gemm_k<<<dim3(8, NSPLIT), 256, 0, stream>>>(syncb, wbt, part);
        reduce_softmax_k<<<128, 256, 0, stream>>>(part, out_b, pred_all, dout, t);
    }
    transpose_pred_k<<<dim3(128, 16), 256, 0, stream>>>(pred_all, dout);
}

// Round 2
// 3536.410 us; speedup vs baseline: 1.1328x; 1.1328x over previous
//
#include <hip/hip_runtime.h>
#include <stdint.h>

#define BB      128
#define DIN     512
#define DMODEL  2048
#define MEMN    25
#define NSY     256
#define OUTD    1000
#define ITERS   24
#define SYNCN   32896
#define KPAD    33280      // padded K for out gemm (26*1280)
#define NPAD    1024
#define NSPLIT  26
#define KCH     1280
#define PREDTOT (BB*OUTD*ITERS)

typedef __attribute__((ext_vector_type(8))) short bf16x8;
typedef __attribute__((ext_vector_type(4))) float f32x4;

__device__ __forceinline__ unsigned short f2bf(float x){
    unsigned int u = __float_as_uint(x);
    u += 0x7fffu + ((u >> 16) & 1u);
    return (unsigned short)(u >> 16);
}
__device__ __forceinline__ float bf2f(unsigned short h){
    unsigned int u = ((unsigned int)h) << 16;
    return __uint_as_float(u);
}
__device__ __forceinline__ float sigm(float x){ return 1.f/(1.f + __expf(-x)); }

// ---------------- init kernels (run every launch: ws is re-poisoned) ----------------

// trace layout: [m][d][b]  (b fastest)
__global__ __launch_bounds__(256) void init_trace_k(const float* __restrict__ st, float* __restrict__ trace){
    const long N = (long)MEMN*DMODEL*BB;
    for (long i = (long)blockIdx.x*256 + threadIdx.x; i < N; i += (long)gridDim.x*256){
        int m = (int)(i / (DMODEL*BB));
        int rem = (int)(i % (DMODEL*BB));
        int d = rem >> 7;
        trace[i] = st[d*MEMN + m];
    }
}

// act layout: [d][b]
__global__ __launch_bounds__(256) void init_act_k(const float* __restrict__ sas, float* __restrict__ act){
    for (int i = blockIdx.x*256 + threadIdx.x; i < DMODEL*BB; i += gridDim.x*256)
        act[i] = sas[i >> 7];
}

__global__ __launch_bounds__(256) void init_alpha_beta_k(const float* __restrict__ sas,
    const int* __restrict__ il, const int* __restrict__ ir,
    float* __restrict__ alpha, float* __restrict__ beta){
    int i = blockIdx.x, tid = threadIdx.x;
    if (tid >= NSY - i) return;
    int j = i + tid;
    int k = i*(2*NSY - i + 1)/2 + tid;
    float a0 = sas[il[i]] * sas[ir[j]];
    beta[k] = 1.f;
    for (int b = 0; b < BB; ++b) alpha[b*SYNCN + k] = a0;
}

// row map for flattened pairwise: rowOf[k] = i, rowstart[i]
__global__ __launch_bounds__(256) void init_rowmap_k(int* __restrict__ rowOf, int* __restrict__ rowstart){
    int i = blockIdx.x, tid = threadIdx.x;
    int start = i*(2*NSY - i + 1)/2;
    int len = NSY - i;
    if (tid == 0) rowstart[i] = start;
    for (int t = tid; t < len; t += 256) rowOf[start + t] = i;
}

// generic f32 transpose: in[R][C] -> out[C][R]
__global__ __launch_bounds__(256) void transpose_f32_k(const float* __restrict__ in, float* __restrict__ out, int R, int C){
    __shared__ float S[64][65];
    int r0 = blockIdx.y*64, c0 = blockIdx.x*64;
    for (int i = threadIdx.x; i < 64*64; i += 256){
        int rr = i >> 6, cc = i & 63;
        int r = r0+rr, c = c0+cc;
        if (r < R && c < C) S[rr][cc] = in[(long)r*C + c];
    }
    __syncthreads();
    for (int i = threadIdx.x; i < 64*64; i += 256){
        int cc = i >> 6, rr = i & 63;
        int r = r0+rr, c = c0+cc;
        if (r < R && c < C) out[(long)c*R + r] = S[rr][cc];
    }
}

// out_w f32 [SYNCN][OUTD] -> bf16 [NPAD][KPAD] (transposed, zero-padded), vectorized
__global__ __launch_bounds__(256) void wbf_transpose_k(const float* __restrict__ w, unsigned short* __restrict__ wt){
    __shared__ float S[64][65];
    int k0 = blockIdx.x*64, n0 = blockIdx.y*64;
    int tid = threadIdx.x;
    bool fast = (k0 + 64 <= SYNCN) && (n0 + 64 <= OUTD);
    if (fast){
#pragma unroll
        for (int p = 0; p < 4; ++p){
            int i = tid + p*256;
            int rr = i >> 4, c4 = (i & 15)*4;
            float4 v = *(const float4*)(w + (long)(k0+rr)*OUTD + n0 + c4);
            S[rr][c4+0]=v.x; S[rr][c4+1]=v.y; S[rr][c4+2]=v.z; S[rr][c4+3]=v.w;
        }
        __syncthreads();
#pragma unroll
        for (int p = 0; p < 4; ++p){
            int i = tid + p*256;
            int nn = i >> 4, k4 = (i & 15)*4;
            ushort2 lo = { f2bf(S[k4+0][nn]), f2bf(S[k4+1][nn]) };
            ushort2 hi = { f2bf(S[k4+2][nn]), f2bf(S[k4+3][nn]) };
            *(ushort2*)(wt + (long)(n0+nn)*KPAD + k0 + k4)     = lo;
            *(ushort2*)(wt + (long)(n0+nn)*KPAD + k0 + k4 + 2) = hi;
        }
    } else {
        for (int i = tid; i < 64*64; i += 256){
            int kk = i >> 6, cc = i & 63;
            int k = k0+kk, n = n0+cc;
            float v = 0.f;
            if (k < SYNCN && n < OUTD) v = w[(long)k*OUTD + n];
            S[kk][cc] = v;
        }
        __syncthreads();
        for (int i = tid; i < 64*64; i += 256){
            int nn = i >> 6, kk = i & 63;
            wt[(long)(n0+nn)*KPAD + (k0+kk)] = f2bf(S[kk][nn]);
        }
    }
}

// syn_w rows [512..2560) f32 [k][4096] -> swT hi/lo bf16 [n=4096][k=2048]
__global__ __launch_bounds__(256) void swt_convert_k(const float* __restrict__ w,
    unsigned short* __restrict__ th, unsigned short* __restrict__ tl){
    __shared__ float S[64][65];
    int k0 = blockIdx.x*64, n0 = blockIdx.y*64;
    int tid = threadIdx.x;
#pragma unroll
    for (int p = 0; p < 4; ++p){
        int i = tid + p*256;
        int rr = i >> 4, c4 = (i & 15)*4;
        float4 v = *(const float4*)(w + (long)(512 + k0 + rr)*4096 + n0 + c4);
        S[rr][c4+0]=v.x; S[rr][c4+1]=v.y; S[rr][c4+2]=v.z; S[rr][c4+3]=v.w;
    }
    __syncthreads();
#pragma unroll
    for (int p = 0; p < 4; ++p){
        int i = tid + p*256;
        int nn = i >> 4, k4 = (i & 15)*4;
        unsigned short h[4], l[4];
#pragma unroll
        for (int q = 0; q < 4; ++q){
            float v = S[k4+q][nn];
            h[q] = f2bf(v);
            l[q] = f2bf(v - bf2f(h[q]));
        }
        *(ushort2*)(th + (long)(n0+nn)*2048 + k0 + k4)     = ushort2{h[0],h[1]};
        *(ushort2*)(th + (long)(n0+nn)*2048 + k0 + k4 + 2) = ushort2{h[2],h[3]};
        *(ushort2*)(tl + (long)(n0+nn)*2048 + k0 + k4)     = ushort2{l[0],l[1]};
        *(ushort2*)(tl + (long)(n0+nn)*2048 + k0 + k4 + 2) = ushort2{l[2],l[3]};
    }
}

// act [d=2048][b=128] f32 -> aT hi/lo bf16 [b][d]
__global__ __launch_bounds__(256) void act_convert_k(const float* __restrict__ act,
    unsigned short* __restrict__ th, unsigned short* __restrict__ tl){
    __shared__ float S[64][65];
    int d0 = blockIdx.x*64, b0 = blockIdx.y*64;
    int tid = threadIdx.x;
#pragma unroll
    for (int p = 0; p < 4; ++p){
        int i = tid + p*256;
        int rr = i >> 4, c4 = (i & 15)*4;
        float4 v = *(const float4*)(act + (long)(d0+rr)*BB + b0 + c4);
        S[rr][c4+0]=v.x; S[rr][c4+1]=v.y; S[rr][c4+2]=v.z; S[rr][c4+3]=v.w;
    }
    __syncthreads();
#pragma unroll
    for (int p = 0; p < 4; ++p){
        int i = tid + p*256;
        int nn = i >> 4, k4 = (i & 15)*4;
        unsigned short h[4], l[4];
#pragma unroll
        for (int q = 0; q < 4; ++q){
            float v = S[k4+q][nn];
            h[q] = f2bf(v);
            l[q] = f2bf(v - bf2f(h[q]));
        }
        *(ushort2*)(th + (long)(b0+nn)*DMODEL + d0 + k4)     = ushort2{h[0],h[1]};
        *(ushort2*)(th + (long)(b0+nn)*DMODEL + d0 + k4 + 2) = ushort2{h[2],h[3]};
        *(ushort2*)(tl + (long)(b0+nn)*DMODEL + d0 + k4)     = ushort2{l[0],l[1]};
        *(ushort2*)(tl + (long)(b0+nn)*DMODEL + d0 + k4 + 2) = ushort2{l[2],l[3]};
    }
}

__global__ __launch_bounds__(256) void sync_pad_k(unsigned short* __restrict__ syncb){
    int b = blockIdx.x;
    for (int k = SYNCN + threadIdx.x; k < KPAD; k += 256) syncb[(long)b*KPAD + k] = 0;
}

// ---------------- per-iteration kernels ----------------

// fp32 GEMM (used once for C0): out[b][j](4096) = bias + sum_k A[k][b]*Bw[k][j], K=512
__global__ __launch_bounds__(256) void gemm_syn_k(const float* __restrict__ A, const float* __restrict__ Bw,
    const float* __restrict__ bias, float* __restrict__ out){
    int j_base = blockIdx.x*64;
    int tid = threadIdx.x;

    __shared__ float As[16][128];
    __shared__ float Bs[16][68];

    int bg = tid & 15, jg = tid >> 4;
    int b0 = bg*8, j0 = jg*4;
    float acc[8][4];
#pragma unroll
    for (int i = 0; i < 8; ++i)
#pragma unroll
        for (int q = 0; q < 4; ++q) acc[i][q] = 0.f;

    for (int kt = 0; kt < 32; ++kt){
        {
            int i0 = tid*8;
            int kk = i0 >> 7, bb = i0 & 127;
            const float4* src = (const float4*)(A + (long)(kt*16+kk)*BB + bb);
            float4 v0 = src[0], v1 = src[1];
            *(float4*)&As[kk][bb]   = v0;
            *(float4*)&As[kk][bb+4] = v1;
        }
        {
            int i0 = tid*4;
            int kk = i0 >> 6, jj = i0 & 63;
            float4 v = *(const float4*)(Bw + (long)(kt*16+kk)*4096 + j_base + jj);
            *(float4*)&Bs[kk][jj] = v;
        }
        __syncthreads();
#pragma unroll
        for (int kk = 0; kk < 16; ++kk){
            float a[8], bv[4];
            *(float4*)&a[0] = *(float4*)&As[kk][b0];
            *(float4*)&a[4] = *(float4*)&As[kk][b0+4];
            *(float4*)&bv[0] = *(float4*)&Bs[kk][j0];
#pragma unroll
            for (int i = 0; i < 8; ++i)
#pragma unroll
                for (int q = 0; q < 4; ++q) acc[i][q] += a[i]*bv[q];
        }
        __syncthreads();
    }
#pragma unroll
    for (int i = 0; i < 8; ++i){
        int bb = b0 + i;
        float4 v;
        v.x = acc[i][0]+bias[j_base+j0+0]; v.y = acc[i][1]+bias[j_base+j0+1];
        v.z = acc[i][2]+bias[j_base+j0+2]; v.w = acc[i][3]+bias[j_base+j0+3];
        *(float4*)(out + (long)bb*4096 + j_base + j0) = v;
    }
}

// bf16 hi/lo MFMA GEMM for syn: zpart[s][128][4096-slice] = actT @ swT^T over K=512 per s
// A: aT hi/lo [128][2048]; B: swT hi/lo [4096][2048]
__global__ __launch_bounds__(256) void syn_mfma_k(const unsigned short* __restrict__ Ah, const unsigned short* __restrict__ Al,
    const unsigned short* __restrict__ Bh, const unsigned short* __restrict__ Bl, float* __restrict__ zpart){
    int nb = blockIdx.x;           // n tile of 64
    int s  = blockIdx.y;           // k split (512 each)
    int tid = threadIdx.x;
    int wid = tid >> 6, lane = tid & 63;
    int wm = (wid & 1)*64, wn = (wid >> 1)*32;

    __shared__ unsigned short As_h[128*40], As_l[128*40], Bs_h[64*40], Bs_l[64*40];
    f32x4 c[4][2];
#pragma unroll
    for (int a = 0; a < 4; ++a)
#pragma unroll
        for (int b = 0; b < 2; ++b) c[a][b] = (f32x4){0.f,0.f,0.f,0.f};

    int mrow = lane & 15, kq = lane >> 4;
    for (int ks = 0; ks < 16; ++ks){
        long koff_base = (long)s*512 + ks*32;
#pragma unroll
        for (int p = 0; p < 2; ++p){
            int idx = tid*2 + p;           // 0..511
            int row = idx >> 2, seg = idx & 3;
            long koff = koff_base + seg*8;
            *(uint4*)&As_h[row*40 + seg*8] = *(const uint4*)(Ah + (long)row*DMODEL + koff);
            *(uint4*)&As_l[row*40 + seg*8] = *(const uint4*)(Al + (long)row*DMODEL + koff);
        }
        {
            int row = tid >> 2, seg = tid & 3;
            long koff = koff_base + seg*8;
            *(uint4*)&Bs_h[row*40 + seg*8] = *(const uint4*)(Bh + (long)(nb*64+row)*DMODEL + koff);
            *(uint4*)&Bs_l[row*40 + seg*8] = *(const uint4*)(Bl + (long)(nb*64+row)*DMODEL + koff);
        }
        __syncthreads();
        bf16x8 ah[4], al[4], bh[2], bl[2];
#pragma unroll
        for (int x = 0; x < 4; ++x){
            ah[x] = *(const bf16x8*)&As_h[(wm + x*16 + mrow)*40 + kq*8];
            al[x] = *(const bf16x8*)&As_l[(wm + x*16 + mrow)*40 + kq*8];
        }
#pragma unroll
        for (int y = 0; y < 2; ++y){
            bh[y] = *(const bf16x8*)&Bs_h[(wn + y*16 + mrow)*40 + kq*8];
            bl[y] = *(const bf16x8*)&Bs_l[(wn + y*16 + mrow)*40 + kq*8];
        }
#pragma unroll
        for (int a = 0; a < 4; ++a)
#pragma unroll
            for (int b = 0; b < 2; ++b){
                c[a][b] = __builtin_amdgcn_mfma_f32_16x16x32_bf16(ah[a], bh[b], c[a][b], 0, 0, 0);
                c[a][b] = __builtin_amdgcn_mfma_f32_16x16x32_bf16(al[a], bh[b], c[a][b], 0, 0, 0);
                c[a][b] = __builtin_amdgcn_mfma_f32_16x16x32_bf16(ah[a], bl[b], c[a][b], 0, 0, 0);
            }
        __syncthreads();
    }
    float* outp = zpart + (long)s*(BB*4096);
#pragma unroll
    for (int a = 0; a < 4; ++a)
#pragma unroll
        for (int b = 0; b < 2; ++b){
            int r0 = wm + a*16 + (lane >> 4)*4;
            int col = nb*64 + wn + b*16 + (lane & 15);
#pragma unroll
            for (int reg = 0; reg < 4; ++reg)
                outp[(long)(r0+reg)*4096 + col] = c[a][b][reg];
        }
}

// GLU + LayerNorm; z = C0 + sum_s zpart[s]; writes state into trace[slot][d][b]
__global__ __launch_bounds__(256) void glu_ln_k(const float* __restrict__ C0, const float* __restrict__ zp,
    const float* __restrict__ lng, const float* __restrict__ lnb, float* __restrict__ trace, int slot){
    int b = blockIdx.x, tid = threadIdx.x;
    __shared__ float sbuf[DMODEL];
    __shared__ float red1[256], red2[256];
    float s1 = 0.f, s2 = 0.f;
#pragma unroll
    for (int q = 0; q < 8; ++q){
        int d = tid + q*256;
        float a = C0[(long)b*4096 + d];
        float g = C0[(long)b*4096 + 2048 + d];
#pragma unroll
        for (int s = 0; s < 4; ++s){
            a += zp[(long)s*524288 + (long)b*4096 + d];
            g += zp[(long)s*524288 + (long)b*4096 + 2048 + d];
        }
        float sv = a * sigm(g);
        sbuf[d] = sv;
        s1 += sv; s2 += sv*sv;
    }
    red1[tid] = s1; red2[tid] = s2; __syncthreads();
    for (int o = 128; o; o >>= 1){
        if (tid < o){ red1[tid] += red1[tid+o]; red2[tid] += red2[tid+o]; }
        __syncthreads();
    }
    float mu = red1[0]*(1.f/2048.f);
    float var = red2[0]*(1.f/2048.f) - mu*mu;
    float inv = rsqrtf(var + 1e-5f);
#pragma unroll
    for (int q = 0; q < 8; ++q){
        int d = tid + q*256;
        float st = (sbuf[d]-mu)*inv*lng[d] + lnb[d];
        trace[(long)slot*(DMODEL*BB) + (long)d*BB + b] = st;
    }
}

// trace_proc: per-d block. h=glu(T@W1+b1) (128x64), o=glu(hh@W2+b2), act=o0
__global__ __launch_bounds__(256) void trace_proc_k(const float* __restrict__ trace, const float* __restrict__ w1t,
    const float* __restrict__ b1, const float* __restrict__ w2t, const float* __restrict__ b2,
    float* __restrict__ act, int t){
    int d = blockIdx.x, tid = threadIdx.x;
    __shared__ float T[MEMN*128];
    __shared__ float W1[MEMN*64];
    __shared__ float hh[128*33];
    __shared__ float w2s[64];
    for (int i = tid; i < MEMN*128; i += 256){
        int m = i >> 7, bb = i & 127;
        int phys = (t + 1 + m) % MEMN;
        T[i] = trace[(long)phys*(DMODEL*BB) + (long)d*BB + bb];
    }
    for (int i = tid; i < 1600; i += 256) W1[i] = w1t[(long)d*1600 + i];
    if (tid < 64) w2s[tid] = w2t[(long)d*64 + tid];
    __syncthreads();

    int bg = tid & 31, jg = tid >> 5;
    int b0 = bg*4, jl = jg*4, jh = jl + 32;
    float accA[4][4], accG[4][4];
    float biasA[4], biasG[4];
#pragma unroll
    for (int q = 0; q < 4; ++q){
        biasA[q] = b1[(long)d*64 + jl + q];
        biasG[q] = b1[(long)d*64 + jh + q];
    }
#pragma unroll
    for (int i = 0; i < 4; ++i)
#pragma unroll
        for (int q = 0; q < 4; ++q){ accA[i][q] = 0.f; accG[i][q] = 0.f; }

    for (int m = 0; m < MEMN; ++m){
        float tv[4], wa[4], wg[4];
        *(float4*)tv = *(float4*)&T[m*128 + b0];
        *(float4*)wa = *(float4*)&W1[m*64 + jl];
        *(float4*)wg = *(float4*)&W1[m*64 + jh];
#pragma unroll
        for (int i = 0; i < 4; ++i)
#pragma unroll
            for (int q = 0; q < 4; ++q){
                accA[i][q] += tv[i]*wa[q];
                accG[i][q] += tv[i]*wg[q];
            }
    }
#pragma unroll
    for (int i = 0; i < 4; ++i)
#pragma unroll
        for (int q = 0; q < 4; ++q){
            float hv = (accA[i][q]+biasA[q]) * sigm(accG[i][q]+biasG[q]);
            hh[(b0+i)*33 + jl + q] = hv;
        }
    __syncthreads();
    if (tid < 128){
        int bb = tid;
        float o0 = b2[(long)d*2+0], o1 = b2[(long)d*2+1];
#pragma unroll
        for (int h = 0; h < 32; ++h){
            float hv = hh[bb*33 + h];
            o0 += hv * w2s[h*2+0];
            o1 += hv * w2s[h*2+1];
        }
        act[(long)d*BB + bb] = o0 * sigm(o1);
    }
}

// pairwise + alpha/beta update + sync (bf16). Flat: 1 thread per sync index.
__global__ __launch_bounds__(256) void pairwise_sync_k(const float* __restrict__ act, const float* __restrict__ decay,
    const int* __restrict__ il, const int* __restrict__ ir,
    const int* __restrict__ rowOf, const int* __restrict__ rowstart,
    float* __restrict__ alpha, float* __restrict__ beta, unsigned short* __restrict__ syncb){
    int k = blockIdx.x*256 + threadIdx.x;
    if (k >= SYNCN) return;
    int i = rowOf[k];
    int j = i + (k - rowstart[i]);
    float r = __expf(-fminf(fmaxf(decay[k], 0.f), 15.f));
    float bet = r*beta[k] + 1.f;
    beta[k] = bet;
    float rs = rsqrtf(bet);
    const float* aL = act + (long)il[i]*BB;
    const float* aR = act + (long)ir[j]*BB;
    for (int b = 0; b < BB; ++b){
        float pp = aL[b]*aR[b];
        float al = r*alpha[(long)b*SYNCN + k] + pp;
        alpha[(long)b*SYNCN + k] = al;
        syncb[(long)b*KPAD + k] = f2bf(al*rs);
    }
}

// bf16 MFMA split-K GEMM: part[sk][128][NPAD] = sync[128][KPAD-chunk] @ w_t^T
__global__ __launch_bounds__(256) void out_gemm_k(const unsigned short* __restrict__ Abf,
    const unsigned short* __restrict__ Bbf, float* __restrict__ part){
    int n_base = blockIdx.x*128;
    int sk = blockIdx.y;
    int tid = threadIdx.x;
    int wid = tid >> 6, lane = tid & 63;
    int wm = (wid & 1)*64, wn = (wid >> 1)*64;
    long k_base = (long)sk*KCH;
    __shared__ unsigned short As[128*40];
    __shared__ unsigned short Bs[128*40];
    f32x4 c[4][4];
#pragma unroll
    for (int a = 0; a < 4; ++a)
#pragma unroll
        for (int b = 0; b < 4; ++b) c[a][b] = (f32x4){0.f,0.f,0.f,0.f};

    int mrow = lane & 15, kq = lane >> 4;
    for (int ks = 0; ks < 40; ++ks){
#pragma unroll
        for (int p = 0; p < 2; ++p){
            int i = tid*2 + p;             // 0..511
            int row = i >> 2, seg = i & 3;
            long koff = k_base + ks*32 + seg*8;
            uint4 va = *(const uint4*)(Abf + (long)row*KPAD + koff);
            *(uint4*)&As[row*40 + seg*8] = va;
            uint4 vb = *(const uint4*)(Bbf + (long)(n_base+row)*KPAD + koff);
            *(uint4*)&Bs[row*40 + seg*8] = vb;
        }
        __syncthreads();
        bf16x8 af[4], bf[4];
#pragma unroll
        for (int x = 0; x < 4; ++x){
            af[x] = *(const bf16x8*)&As[(wm + x*16 + mrow)*40 + kq*8];
            bf[x] = *(const bf16x8*)&Bs[(wn + x*16 + mrow)*40 + kq*8];
        }
#pragma unroll
        for (int a = 0; a < 4; ++a)
#pragma unroll
            for (int b = 0; b < 4; ++b)
                c[a][b] = __builtin_amdgcn_mfma_f32_16x16x32_bf16(af[a], bf[b], c[a][b], 0, 0, 0);
        __syncthreads();
    }
    float* outp = part + (long)sk*(128*NPAD);
#pragma unroll
    for (int a = 0; a < 4; ++a)
#pragma unroll
        for (int b = 0; b < 4; ++b){
            int r0 = wm + a*16 + (lane >> 4)*4;
            int col = n_base + wn + b*16 + (lane & 15);
#pragma unroll
            for (int reg = 0; reg < 4; ++reg)
                outp[(long)(r0+reg)*NPAD + col] = c[a][b][reg];
        }
}

// reduce split-K partials + bias, entropy, write pred_all[t][b][n] and certainties
__global__ __launch_bounds__(256) void reduce_softmax_k(const float* __restrict__ part, const float* __restrict__ outb,
    float* __restrict__ pred_all, float* __restrict__ dout, int t){
    int b = blockIdx.x, tid = threadIdx.x;
    __shared__ float red[256];
    float v[4];
    float lmax = -1e30f;
#pragma unroll
    for (int q = 0; q < 4; ++q){
        int n = tid + q*256;
        float s = -1e30f;
        if (n < OUTD){
            s = outb[n];
            for (int sk = 0; sk < NSPLIT; ++sk) s += part[(long)sk*(128*NPAD) + (long)b*NPAD + n];
        }
        v[q] = s;
        lmax = fmaxf(lmax, s);
    }
    red[tid] = lmax; __syncthreads();
    for (int o = 128; o; o >>= 1){ if (tid < o) red[tid] = fmaxf(red[tid], red[tid+o]); __syncthreads(); }
    float M = red[0]; __syncthreads();
    float z = 0.f, sv = 0.f;
#pragma unroll
    for (int q = 0; q < 4; ++q){
        int n = tid + q*256;
        if (n < OUTD){
            float e = __expf(v[q]-M);
            z += e; sv += e*v[q];
        }
    }
    red[tid] = z; __syncthreads();
    for (int o = 128; o; o >>= 1){ if (tid < o) red[tid] += red[tid+o]; __syncthreads(); }
    float Z = red[0]; __syncthreads();
    red[tid] = sv; __syncthreads();
    for (int o = 128; o; o >>= 1){ if (tid < o) red[tid] += red[tid+o]; __syncthreads(); }
    float S = red[0];
    if (tid == 0){
        float logZ = M + __logf(Z);
        float ne = (logZ - S/Z) / 6.907755278982137f;
        dout[PREDTOT + b*48 + t] = ne;
        dout[PREDTOT + b*48 + 24 + t] = 1.f - ne;
    }
#pragma unroll
    for (int q = 0; q < 4; ++q){
        int n = tid + q*256;
        if (n < OUTD) pred_all[(long)t*(BB*OUTD) + (long)b*OUTD + n] = v[q];
    }
}

// pred_all [t][b][n] -> d_out [b][n][t]
__global__ __launch_bounds__(256) void transpose_pred_k(const float* __restrict__ pa, float* __restrict__ dout){
    int b = blockIdx.x;
    int n0 = blockIdx.y*64;
    __shared__ float S[64][25];
    for (int i = threadIdx.x; i < 24*64; i += 256){
        int tt = i >> 6, j = i & 63;
        int n = n0 + j;
        if (n < OUTD) S[j][tt] = pa[(long)tt*(BB*OUTD) + (long)b*OUTD + n];
    }
    __syncthreads();
    for (int i = threadIdx.x; i < 64*24; i += 256){
        int j = i / 24, tt = i % 24;
        int n = n0 + j;
        if (n < OUTD) dout[(long)b*(OUTD*ITERS) + (long)n*ITERS + tt] = S[j][tt];
    }
}

// ---------------- host ----------------

extern "C" void kernel_launch(void* const* d_in, const int* in_sizes, int n_in,
                              void* d_out, int out_size, void* d_ws, size_t ws_size,
                              hipStream_t stream){
    const float* x      = (const float*)d_in[0];
    const float* syn_w  = (const float*)d_in[1];
    const float* syn_b  = (const float*)d_in[2];
    const float* ln_g   = (const float*)d_in[3];
    const float* ln_b   = (const float*)d_in[4];
    const float* tp_w1  = (const float*)d_in[5];
    const float* tp_b1  = (const float*)d_in[6];
    const float* tp_w2  = (const float*)d_in[7];
    const float* tp_b2  = (const float*)d_in[8];
    const float* sas    = (const float*)d_in[9];
    const float* strc   = (const float*)d_in[10];
    const float* decay  = (const float*)d_in[11];
    const float* out_w  = (const float*)d_in[12];
    const float* out_b  = (const float*)d_in[13];
    const int*   il     = (const int*)d_in[14];
    const int*   ir     = (const int*)d_in[15];
    float* dout = (float*)d_out;

    char* ws = (char*)d_ws;
    size_t off = 0;
    auto alloc = [&](size_t bytes)->void*{
        void* p = ws + off;
        off += (bytes + 255) & ~(size_t)255;
        return p;
    };
    float* trace   = (float*)alloc((size_t)MEMN*DMODEL*BB*4);     // 26.2 MB  [m][d][b]
    float* act     = (float*)alloc((size_t)DMODEL*BB*4);          // 1 MB     [d][b]
    float* C0      = (float*)alloc((size_t)BB*4096*4);            // 2.1 MB
    float* xt      = (float*)alloc((size_t)DIN*BB*4);             // 0.26 MB  [k][b]
    float* w1t     = (float*)alloc((size_t)DMODEL*1600*4);        // 13.1 MB  [d][m*64+j]
    float* w2t     = (float*)alloc((size_t)DMODEL*64*4);          // 0.52 MB  [d][h*2+o]
    float* alpha   = (float*)alloc((size_t)BB*SYNCN*4);           // 16.8 MB
    float* beta    = (float*)alloc((size_t)SYNCN*4);              // 0.13 MB
    unsigned short* syncb = (unsigned short*)alloc((size_t)BB*KPAD*2);   // 8.5 MB  [b][k]
    unsigned short* wbt   = (unsigned short*)alloc((size_t)NPAD*KPAD*2); // 68.2 MB [n][k]
    float* pred_all= (float*)alloc((size_t)ITERS*BB*OUTD*4);      // 12.3 MB
    // zpart (4*128*4096*4 = 8.4 MB) and part (26*128*1024*4 = 13.6 MB) share one
    // region: zpart live [syn_mfma -> glu_ln], part live [out_gemm -> reduce].
    float* shared_big = (float*)alloc((size_t)NSPLIT*BB*NPAD*4);  // 13.6 MB
    float* zpart = shared_big;
    float* part  = shared_big;
    unsigned short* swT_h = (unsigned short*)alloc((size_t)4096*DMODEL*2); // 16.8 MB [n][k]
    unsigned short* swT_l = (unsigned short*)alloc((size_t)4096*DMODEL*2); // 16.8 MB
    unsigned short* aT_h  = (unsigned short*)alloc((size_t)BB*DMODEL*2);   // 0.52 MB [b][d]
    unsigned short* aT_l  = (unsigned short*)alloc((size_t)BB*DMODEL*2);   // 0.52 MB
    int* rowOf    = (int*)alloc((size_t)SYNCN*4);                 // 0.13 MB
    int* rowstart = (int*)alloc((size_t)NSY*4);
    (void)ws_size; (void)in_sizes; (void)n_in; (void)out_size;

    // ---- once-per-launch precompute ----
    init_trace_k<<<8192, 256, 0, stream>>>(strc, trace);
    init_act_k<<<1024, 256, 0, stream>>>(sas, act);
    init_alpha_beta_k<<<256, 256, 0, stream>>>(sas, il, ir, alpha, beta);
    init_rowmap_k<<<256, 256, 0, stream>>>(rowOf, rowstart);
    transpose_f32_k<<<dim3(32, 25), 256, 0, stream>>>(tp_w1, w1t, 1600, 2048);
    transpose_f32_k<<<dim3(32, 1),  256, 0, stream>>>(tp_w2, w2t, 64, 2048);
    transpose_f32_k<<<dim3(8, 2),   256, 0, stream>>>(x, xt, 128, 512);
    wbf_transpose_k<<<dim3(520, 16), 256, 0, stream>>>(out_w, wbt);
    swt_convert_k<<<dim3(32, 64), 256, 0, stream>>>(syn_w, swT_h, swT_l);
    sync_pad_k<<<128, 256, 0, stream>>>(syncb);
    // C0 = syn_b + x @ syn_w[0:512]
    gemm_syn_k<<<64, 256, 0, stream>>>(xt, syn_w, syn_b, C0);
    // initial act -> bf16 hi/lo transposed
    act_convert_k<<<dim3(32, 2), 256, 0, stream>>>(act, aT_h, aT_l);

    // ---- 24 sequential iterations ----
    for (int t = 0; t < ITERS; ++t){
        syn_mfma_k<<<dim3(64, 4), 256, 0, stream>>>(aT_h, aT_l, swT_h, swT_l, zpart);
        glu_ln_k<<<128, 256, 0, stream>>>(C0, zpart, ln_g, ln_b, trace, t % MEMN);
        trace_proc_k<<<2048, 256, 0, stream>>>(trace, w1t, tp_b1, w2t, tp_b2, act, t);
        act_convert_k<<<dim3(32, 2), 256, 0, stream>>>(act, aT_h, aT_l);
        pairwise_sync_k<<<129, 256, 0, stream>>>(act, decay, il, ir, rowOf, rowstart, alpha, beta, syncb);
        out_gemm_k<<<dim3(8, NSPLIT), 256, 0, stream>>>(syncb, wbt, part);
        reduce_softmax_k<<<128, 256, 0, stream>>>(part, out_b, pred_all, dout, t);
    }
    transpose_pred_k<<<dim3(128, 16), 256, 0, stream>>>(pred_all, dout);
}

// Round 3
// 3188.335 us; speedup vs baseline: 1.2564x; 1.1092x over previous
//
#include <hip/hip_runtime.h>
#include <stdint.h>

#define BB      128
#define DIN     512
#define DMODEL  2048
#define MEMN    25
#define NSY     256
#define OUTD    1000
#define ITERS   24
#define SYNCN   32896
#define KPAD    33280      // padded K for out gemm (52*640)
#define NPAD    1024
#define NSPLIT  52
#define KCH     640
#define PREDTOT (BB*OUTD*ITERS)

typedef __attribute__((ext_vector_type(8))) short bf16x8;
typedef __attribute__((ext_vector_type(4))) float f32x4;

__device__ __forceinline__ unsigned short f2bf(float x){
    unsigned int u = __float_as_uint(x);
    u += 0x7fffu + ((u >> 16) & 1u);
    return (unsigned short)(u >> 16);
}
__device__ __forceinline__ float bf2f(unsigned short h){
    unsigned int u = ((unsigned int)h) << 16;
    return __uint_as_float(u);
}
__device__ __forceinline__ float sigm(float x){ return 1.f/(1.f + __expf(-x)); }

// ---------------- init kernels (run every launch: ws is re-poisoned) ----------------

// trace stored as bf16 hi/lo pair, layout [m][d][b] (b fastest)
__global__ __launch_bounds__(256) void init_trace_k(const float* __restrict__ st,
    unsigned short* __restrict__ trh, unsigned short* __restrict__ trl){
    const long N = (long)MEMN*DMODEL*BB;
    for (long i = (long)blockIdx.x*256 + threadIdx.x; i < N; i += (long)gridDim.x*256){
        int m = (int)(i / (DMODEL*BB));
        int rem = (int)(i % (DMODEL*BB));
        int d = rem >> 7;
        float v = st[d*MEMN + m];
        unsigned short h = f2bf(v);
        trh[i] = h;
        trl[i] = f2bf(v - bf2f(h));
    }
}

// act layout: [d][b]
__global__ __launch_bounds__(256) void init_act_k(const float* __restrict__ sas, float* __restrict__ act){
    for (int i = blockIdx.x*256 + threadIdx.x; i < DMODEL*BB; i += gridDim.x*256)
        act[i] = sas[i >> 7];
}

__global__ __launch_bounds__(256) void init_alpha_beta_k(const float* __restrict__ sas,
    const int* __restrict__ il, const int* __restrict__ ir,
    float* __restrict__ alpha, float* __restrict__ beta){
    int i = blockIdx.x, tid = threadIdx.x;
    if (tid >= NSY - i) return;
    int j = i + tid;
    int k = i*(2*NSY - i + 1)/2 + tid;
    float a0 = sas[il[i]] * sas[ir[j]];
    beta[k] = 1.f;
    for (int b = 0; b < BB; ++b) alpha[b*SYNCN + k] = a0;
}

__global__ __launch_bounds__(256) void init_rowmap_k(int* __restrict__ rowOf, int* __restrict__ rowstart){
    int i = blockIdx.x, tid = threadIdx.x;
    int start = i*(2*NSY - i + 1)/2;
    int len = NSY - i;
    if (tid == 0) rowstart[i] = start;
    for (int t = tid; t < len; t += 256) rowOf[start + t] = i;
}

// generic f32 transpose: in[R][C] -> out[C][R]
__global__ __launch_bounds__(256) void transpose_f32_k(const float* __restrict__ in, float* __restrict__ out, int R, int C){
    __shared__ float S[64][65];
    int r0 = blockIdx.y*64, c0 = blockIdx.x*64;
    for (int i = threadIdx.x; i < 64*64; i += 256){
        int rr = i >> 6, cc = i & 63;
        int r = r0+rr, c = c0+cc;
        if (r < R && c < C) S[rr][cc] = in[(long)r*C + c];
    }
    __syncthreads();
    for (int i = threadIdx.x; i < 64*64; i += 256){
        int cc = i >> 6, rr = i & 63;
        int r = r0+rr, c = c0+cc;
        if (r < R && c < C) out[(long)c*R + r] = S[rr][cc];
    }
}

// w1t [d][m*64+h] f32 -> w1bf [d][plane(hi=0,lo=1)][h*40+m] bf16, m padded 25->40 with zeros
__global__ __launch_bounds__(256) void w1bf_prep_k(const float* __restrict__ w1t, unsigned short* __restrict__ w1bf){
    int d = blockIdx.x, tid = threadIdx.x;
    __shared__ float S[1600];
    for (int i = tid; i < 1600; i += 256) S[i] = w1t[(long)d*1600 + i];
    __syncthreads();
    for (int i = tid; i < 2560; i += 256){
        int h = i/40, m = i - h*40;
        float v = (m < MEMN) ? S[m*64 + h] : 0.f;
        unsigned short hi = f2bf(v);
        unsigned short lo = f2bf(v - bf2f(hi));
        w1bf[(long)d*5120 + i]        = hi;
        w1bf[(long)d*5120 + 2560 + i] = lo;
    }
}

// out_w f32 [SYNCN][OUTD] -> bf16 [NPAD][KPAD] (transposed, zero-padded)
// macro-tile 64k x 256n; transpose-on-store LDS S_T[n][k] stride 65 (both phases <=2-way conflicts)
__global__ __launch_bounds__(256) void wbf_transpose_k(const float* __restrict__ w, unsigned short* __restrict__ wt){
    __shared__ float ST[256][65];
    int k0 = blockIdx.x*64, n0 = blockIdx.y*256;
    int tid = threadIdx.x;
#pragma unroll
    for (int p = 0; p < 16; ++p){
        int i = tid + p*256;               // 0..4095
        int rr = i >> 6, c4 = (i & 63)*4;  // rr: k-row 0..63, c4: n-col 0..252
        int k = k0 + rr;
        float4 v = {0.f,0.f,0.f,0.f};
        if (k < SYNCN){
            int n = n0 + c4;
            if (n + 3 < OUTD) v = *(const float4*)(w + (long)k*OUTD + n);
            else {
                float t0 = (n+0 < OUTD) ? w[(long)k*OUTD + n+0] : 0.f;
                float t1 = (n+1 < OUTD) ? w[(long)k*OUTD + n+1] : 0.f;
                float t2 = (n+2 < OUTD) ? w[(long)k*OUTD + n+2] : 0.f;
                float t3 = (n+3 < OUTD) ? w[(long)k*OUTD + n+3] : 0.f;
                v = float4{t0,t1,t2,t3};
            }
        }
        ST[c4+0][rr] = v.x; ST[c4+1][rr] = v.y; ST[c4+2][rr] = v.z; ST[c4+3][rr] = v.w;
    }
    __syncthreads();
#pragma unroll
    for (int p = 0; p < 16; ++p){
        int i = tid + p*256;               // 0..4095
        int nn = i >> 4, k4 = (i & 15)*4;  // nn 0..255, k4 0..60
        ushort4 o;
        o.x = f2bf(ST[nn][k4+0]); o.y = f2bf(ST[nn][k4+1]);
        o.z = f2bf(ST[nn][k4+2]); o.w = f2bf(ST[nn][k4+3]);
        *(ushort4*)(wt + (long)(n0+nn)*KPAD + k0 + k4) = o;
    }
}

// syn_w rows [512..2560) f32 [k][4096] -> swT hi/lo bf16 [n=4096][k=2048]; macro-tile 64k x 256n
__global__ __launch_bounds__(256) void swt_convert_k(const float* __restrict__ w,
    unsigned short* __restrict__ th, unsigned short* __restrict__ tl){
    __shared__ float ST[256][65];
    int k0 = blockIdx.x*64, n0 = blockIdx.y*256;
    int tid = threadIdx.x;
#pragma unroll
    for (int p = 0; p < 16; ++p){
        int i = tid + p*256;
        int rr = i >> 6, c4 = (i & 63)*4;
        float4 v = *(const float4*)(w + (long)(512 + k0 + rr)*4096 + n0 + c4);
        ST[c4+0][rr] = v.x; ST[c4+1][rr] = v.y; ST[c4+2][rr] = v.z; ST[c4+3][rr] = v.w;
    }
    __syncthreads();
#pragma unroll
    for (int p = 0; p < 16; ++p){
        int i = tid + p*256;
        int nn = i >> 4, k4 = (i & 15)*4;
        ushort4 oh, ol;
        float v0 = ST[nn][k4+0], v1 = ST[nn][k4+1], v2 = ST[nn][k4+2], v3 = ST[nn][k4+3];
        oh.x = f2bf(v0); oh.y = f2bf(v1); oh.z = f2bf(v2); oh.w = f2bf(v3);
        ol.x = f2bf(v0 - bf2f(oh.x)); ol.y = f2bf(v1 - bf2f(oh.y));
        ol.z = f2bf(v2 - bf2f(oh.z)); ol.w = f2bf(v3 - bf2f(oh.w));
        *(ushort4*)(th + (long)(n0+nn)*DMODEL + k0 + k4) = oh;
        *(ushort4*)(tl + (long)(n0+nn)*DMODEL + k0 + k4) = ol;
    }
}

// act [d=2048][b=128] f32 -> aT hi/lo bf16 [b][d]  (init only; per-iter fused into trace_proc)
__global__ __launch_bounds__(256) void act_convert_k(const float* __restrict__ act,
    unsigned short* __restrict__ th, unsigned short* __restrict__ tl){
    __shared__ float S[64][65];
    int d0 = blockIdx.x*64, b0 = blockIdx.y*64;
    int tid = threadIdx.x;
#pragma unroll
    for (int p = 0; p < 4; ++p){
        int i = tid + p*256;
        int rr = i >> 4, c4 = (i & 15)*4;
        float4 v = *(const float4*)(act + (long)(d0+rr)*BB + b0 + c4);
        S[rr][c4+0]=v.x; S[rr][c4+1]=v.y; S[rr][c4+2]=v.z; S[rr][c4+3]=v.w;
    }
    __syncthreads();
#pragma unroll
    for (int p = 0; p < 4; ++p){
        int i = tid + p*256;
        int nn = i >> 4, k4 = (i & 15)*4;
        unsigned short h[4], l[4];
#pragma unroll
        for (int q = 0; q < 4; ++q){
            float v = S[k4+q][nn];
            h[q] = f2bf(v);
            l[q] = f2bf(v - bf2f(h[q]));
        }
        *(ushort2*)(th + (long)(b0+nn)*DMODEL + d0 + k4)     = ushort2{h[0],h[1]};
        *(ushort2*)(th + (long)(b0+nn)*DMODEL + d0 + k4 + 2) = ushort2{h[2],h[3]};
        *(ushort2*)(tl + (long)(b0+nn)*DMODEL + d0 + k4)     = ushort2{l[0],l[1]};
        *(ushort2*)(tl + (long)(b0+nn)*DMODEL + d0 + k4 + 2) = ushort2{l[2],l[3]};
    }
}

__global__ __launch_bounds__(256) void sync_pad_k(unsigned short* __restrict__ syncb){
    int b = blockIdx.x;
    for (int k = SYNCN + threadIdx.x; k < KPAD; k += 256) syncb[(long)b*KPAD + k] = 0;
}

// fp32 GEMM (once, for C0): out[b][j](4096) = bias + sum_k A[k][b]*Bw[k][j], K=512
__global__ __launch_bounds__(256) void gemm_syn_k(const float* __restrict__ A, const float* __restrict__ Bw,
    const float* __restrict__ bias, float* __restrict__ out){
    int j_base = blockIdx.x*64;
    int tid = threadIdx.x;
    __shared__ float As[16][128];
    __shared__ float Bs[16][68];
    int bg = tid & 15, jg = tid >> 4;
    int b0 = bg*8, j0 = jg*4;
    float acc[8][4];
#pragma unroll
    for (int i = 0; i < 8; ++i)
#pragma unroll
        for (int q = 0; q < 4; ++q) acc[i][q] = 0.f;
    for (int kt = 0; kt < 32; ++kt){
        {
            int i0 = tid*8;
            int kk = i0 >> 7, bb = i0 & 127;
            const float4* src = (const float4*)(A + (long)(kt*16+kk)*BB + bb);
            float4 v0 = src[0], v1 = src[1];
            *(float4*)&As[kk][bb]   = v0;
            *(float4*)&As[kk][bb+4] = v1;
        }
        {
            int i0 = tid*4;
            int kk = i0 >> 6, jj = i0 & 63;
            float4 v = *(const float4*)(Bw + (long)(kt*16+kk)*4096 + j_base + jj);
            *(float4*)&Bs[kk][jj] = v;
        }
        __syncthreads();
#pragma unroll
        for (int kk = 0; kk < 16; ++kk){
            float a[8], bv[4];
            *(float4*)&a[0] = *(float4*)&As[kk][b0];
            *(float4*)&a[4] = *(float4*)&As[kk][b0+4];
            *(float4*)&bv[0] = *(float4*)&Bs[kk][j0];
#pragma unroll
            for (int i = 0; i < 8; ++i)
#pragma unroll
                for (int q = 0; q < 4; ++q) acc[i][q] += a[i]*bv[q];
        }
        __syncthreads();
    }
#pragma unroll
    for (int i = 0; i < 8; ++i){
        int bb = b0 + i;
        float4 v;
        v.x = acc[i][0]+bias[j_base+j0+0]; v.y = acc[i][1]+bias[j_base+j0+1];
        v.z = acc[i][2]+bias[j_base+j0+2]; v.w = acc[i][3]+bias[j_base+j0+3];
        *(float4*)(out + (long)bb*4096 + j_base + j0) = v;
    }
}

// ---------------- per-iteration kernels ----------------

// bf16 hi/lo MFMA GEMM for syn: zpart[s][128][4096-slice] = actT @ swT^T over K=512 per s
__global__ __launch_bounds__(256) void syn_mfma_k(const unsigned short* __restrict__ Ah, const unsigned short* __restrict__ Al,
    const unsigned short* __restrict__ Bh, const unsigned short* __restrict__ Bl, float* __restrict__ zpart){
    int nb = blockIdx.x;
    int s  = blockIdx.y;
    int tid = threadIdx.x;
    int wid = tid >> 6, lane = tid & 63;
    int wm = (wid & 1)*64, wn = (wid >> 1)*32;

    __shared__ unsigned short As_h[128*40], As_l[128*40], Bs_h[64*40], Bs_l[64*40];
    f32x4 c[4][2];
#pragma unroll
    for (int a = 0; a < 4; ++a)
#pragma unroll
        for (int b = 0; b < 2; ++b) c[a][b] = (f32x4){0.f,0.f,0.f,0.f};

    int mrow = lane & 15, kq = lane >> 4;
    for (int ks = 0; ks < 16; ++ks){
        long koff_base = (long)s*512 + ks*32;
#pragma unroll
        for (int p = 0; p < 2; ++p){
            int idx = tid*2 + p;
            int row = idx >> 2, seg = idx & 3;
            long koff = koff_base + seg*8;
            *(uint4*)&As_h[row*40 + seg*8] = *(const uint4*)(Ah + (long)row*DMODEL + koff);
            *(uint4*)&As_l[row*40 + seg*8] = *(const uint4*)(Al + (long)row*DMODEL + koff);
        }
        {
            int row = tid >> 2, seg = tid & 3;
            long koff = koff_base + seg*8;
            *(uint4*)&Bs_h[row*40 + seg*8] = *(const uint4*)(Bh + (long)(nb*64+row)*DMODEL + koff);
            *(uint4*)&Bs_l[row*40 + seg*8] = *(const uint4*)(Bl + (long)(nb*64+row)*DMODEL + koff);
        }
        __syncthreads();
        bf16x8 ah[4], al[4], bh[2], bl[2];
#pragma unroll
        for (int x = 0; x < 4; ++x){
            ah[x] = *(const bf16x8*)&As_h[(wm + x*16 + mrow)*40 + kq*8];
            al[x] = *(const bf16x8*)&As_l[(wm + x*16 + mrow)*40 + kq*8];
        }
#pragma unroll
        for (int y = 0; y < 2; ++y){
            bh[y] = *(const bf16x8*)&Bs_h[(wn + y*16 + mrow)*40 + kq*8];
            bl[y] = *(const bf16x8*)&Bs_l[(wn + y*16 + mrow)*40 + kq*8];
        }
#pragma unroll
        for (int a = 0; a < 4; ++a)
#pragma unroll
            for (int b = 0; b < 2; ++b){
                c[a][b] = __builtin_amdgcn_mfma_f32_16x16x32_bf16(ah[a], bh[b], c[a][b], 0, 0, 0);
                c[a][b] = __builtin_amdgcn_mfma_f32_16x16x32_bf16(al[a], bh[b], c[a][b], 0, 0, 0);
                c[a][b] = __builtin_amdgcn_mfma_f32_16x16x32_bf16(ah[a], bl[b], c[a][b], 0, 0, 0);
            }
        __syncthreads();
    }
    float* outp = zpart + (long)s*(BB*4096);
#pragma unroll
    for (int a = 0; a < 4; ++a)
#pragma unroll
        for (int b = 0; b < 2; ++b){
            int r0 = wm + a*16 + (lane >> 4)*4;
            int col = nb*64 + wn + b*16 + (lane & 15);
#pragma unroll
            for (int reg = 0; reg < 4; ++reg)
                outp[(long)(r0+reg)*4096 + col] = c[a][b][reg];
        }
}

// GLU + LayerNorm, 1024 threads (16 waves); writes state as bf16 hi/lo into trace ring slot
__global__ __launch_bounds__(1024) void glu_ln_k(const float* __restrict__ C0, const float* __restrict__ zp,
    const float* __restrict__ lng, const float* __restrict__ lnb,
    unsigned short* __restrict__ trh, unsigned short* __restrict__ trl, int slot){
    int b = blockIdx.x, tid = threadIdx.x;
    __shared__ float redA[16], redB[16];
    float sv[2];
    float s1 = 0.f, s2 = 0.f;
#pragma unroll
    for (int q = 0; q < 2; ++q){
        int d = tid + q*1024;
        float a = C0[(long)b*4096 + d];
        float g = C0[(long)b*4096 + 2048 + d];
#pragma unroll
        for (int s = 0; s < 4; ++s){
            a += zp[(long)s*524288 + (long)b*4096 + d];
            g += zp[(long)s*524288 + (long)b*4096 + 2048 + d];
        }
        float v = a * sigm(g);
        sv[q] = v;
        s1 += v; s2 += v*v;
    }
#pragma unroll
    for (int off = 32; off; off >>= 1){
        s1 += __shfl_down(s1, off);
        s2 += __shfl_down(s2, off);
    }
    if ((tid & 63) == 0){ redA[tid>>6] = s1; redB[tid>>6] = s2; }
    __syncthreads();
    if (tid == 0){
        float a = 0.f, bsum = 0.f;
        for (int i = 0; i < 16; ++i){ a += redA[i]; bsum += redB[i]; }
        float mu = a*(1.f/2048.f);
        float var = bsum*(1.f/2048.f) - mu*mu;
        redA[0] = mu;
        redB[0] = rsqrtf(var + 1e-5f);
    }
    __syncthreads();
    float mu = redA[0], inv = redB[0];
#pragma unroll
    for (int q = 0; q < 2; ++q){
        int d = tid + q*1024;
        float st = (sv[q]-mu)*inv*lng[d] + lnb[d];
        unsigned short h = f2bf(st);
        trh[(long)slot*(DMODEL*BB) + (long)d*BB + b] = h;
        trl[(long)slot*(DMODEL*BB) + (long)d*BB + b] = f2bf(st - bf2f(h));
    }
}

// trace_proc via bf16 hi/lo MFMA. Per-d block: A=T[128b][32m], B=W1[32m][64h] (pre-packed).
// Epilogue: GLU -> hh, tiny second GEMM, act write + fused aT hi/lo convert.
__global__ __launch_bounds__(256) void trace_proc_k(
    const unsigned short* __restrict__ trh, const unsigned short* __restrict__ trl,
    const unsigned short* __restrict__ w1bf,
    const float* __restrict__ b1, const float* __restrict__ w2t, const float* __restrict__ b2,
    float* __restrict__ act, unsigned short* __restrict__ aTh, unsigned short* __restrict__ aTl, int t){
    int d = blockIdx.x, tid = threadIdx.x;
    __shared__ __align__(16) unsigned short Ah[128*40];
    __shared__ __align__(16) unsigned short Al[128*40];
    __shared__ __align__(16) unsigned short Bbuf[5120];   // hi plane [0,2560), lo plane [2560,5120)
    __shared__ float hh[128*33];
    __shared__ float w2s[64];

    // stage A (trace -> [b][m] hi/lo) with on-the-fly transpose
    for (int i = tid; i < MEMN*64; i += 256){
        int m = i >> 6, bp = i & 63;
        int phys = t + 1 + m; if (phys >= MEMN) phys -= MEMN; if (phys >= MEMN) phys -= MEMN;
        long gaddr = ((long)phys*DMODEL + d)*BB + bp*2;
        ushort2 vh = *(const ushort2*)(trh + gaddr);
        ushort2 vl = *(const ushort2*)(trl + gaddr);
        Ah[(bp*2+0)*40 + m] = vh.x; Ah[(bp*2+1)*40 + m] = vh.y;
        Al[(bp*2+0)*40 + m] = vl.x; Al[(bp*2+1)*40 + m] = vl.y;
    }
    // zero-pad m = 25..31
    for (int i = tid; i < 7*128; i += 256){
        int m = MEMN + (i >> 7), b = i & 127;
        Ah[b*40 + m] = 0; Al[b*40 + m] = 0;
    }
    // stage B (w1bf, already packed [h*40+m] hi then lo)
    {
        const uint4* src = (const uint4*)(w1bf + (long)d*5120);
        uint4* dst = (uint4*)Bbuf;
        for (int i = tid; i < 640; i += 256) dst[i] = src[i];
    }
    if (tid < 64) w2s[tid] = w2t[(long)d*64 + tid];
    __syncthreads();

    int wid = tid >> 6, lane = tid & 63;
    int mrow = lane & 15, kq = lane >> 4;
    bf16x8 ahf[2], alf[2], bhf[4], blf[4];
#pragma unroll
    for (int bt = 0; bt < 2; ++bt){
        int r = (wid*2 + bt)*16 + mrow;
        ahf[bt] = *(const bf16x8*)&Ah[r*40 + kq*8];
        alf[bt] = *(const bf16x8*)&Al[r*40 + kq*8];
    }
#pragma unroll
    for (int ht = 0; ht < 4; ++ht){
        int r = ht*16 + mrow;
        bhf[ht] = *(const bf16x8*)&Bbuf[r*40 + kq*8];
        blf[ht] = *(const bf16x8*)&Bbuf[2560 + r*40 + kq*8];
    }
    f32x4 c[2][4];
#pragma unroll
    for (int bt = 0; bt < 2; ++bt)
#pragma unroll
        for (int ht = 0; ht < 4; ++ht){
            c[bt][ht] = (f32x4){0.f,0.f,0.f,0.f};
            c[bt][ht] = __builtin_amdgcn_mfma_f32_16x16x32_bf16(ahf[bt], bhf[ht], c[bt][ht], 0, 0, 0);
            c[bt][ht] = __builtin_amdgcn_mfma_f32_16x16x32_bf16(alf[bt], bhf[ht], c[bt][ht], 0, 0, 0);
            c[bt][ht] = __builtin_amdgcn_mfma_f32_16x16x32_bf16(ahf[bt], blf[ht], c[bt][ht], 0, 0, 0);
        }
    // GLU epilogue into hh[128][32]
    int quad = lane >> 4;
#pragma unroll
    for (int bt = 0; bt < 2; ++bt){
        int bb0 = (wid*2 + bt)*16 + quad*4;
#pragma unroll
        for (int ht = 0; ht < 2; ++ht){
            int h = ht*16 + (lane & 15);
            float ba = b1[(long)d*64 + h];
            float bg = b1[(long)d*64 + 32 + h];
#pragma unroll
            for (int reg = 0; reg < 4; ++reg){
                float a = c[bt][ht][reg] + ba;
                float g = c[bt][ht+2][reg] + bg;
                hh[(bb0+reg)*33 + h] = a * sigm(g);
            }
        }
    }
    __syncthreads();
    if (tid < 128){
        int bb = tid;
        float o0 = b2[(long)d*2+0], o1 = b2[(long)d*2+1];
#pragma unroll
        for (int h = 0; h < 32; ++h){
            float hv = hh[bb*33 + h];
            o0 += hv * w2s[h*2+0];
            o1 += hv * w2s[h*2+1];
        }
        float a = o0 * sigm(o1);
        act[(long)d*BB + bb] = a;
        unsigned short h16 = f2bf(a);
        aTh[(long)bb*DMODEL + d] = h16;
        aTl[(long)bb*DMODEL + d] = f2bf(a - bf2f(h16));
    }
}

// pairwise + alpha/beta update + sync (bf16). Flat: 1 thread per sync index.
__global__ __launch_bounds__(256) void pairwise_sync_k(const float* __restrict__ act, const float* __restrict__ decay,
    const int* __restrict__ il, const int* __restrict__ ir,
    const int* __restrict__ rowOf, const int* __restrict__ rowstart,
    float* __restrict__ alpha, float* __restrict__ beta, unsigned short* __restrict__ syncb){
    int k = blockIdx.x*256 + threadIdx.x;
    if (k >= SYNCN) return;
    int i = rowOf[k];
    int j = i + (k - rowstart[i]);
    float r = __expf(-fminf(fmaxf(decay[k], 0.f), 15.f));
    float bet = r*beta[k] + 1.f;
    beta[k] = bet;
    float rs = rsqrtf(bet);
    const float* aL = act + (long)il[i]*BB;
    const float* aR = act + (long)ir[j]*BB;
    for (int b = 0; b < BB; ++b){
        float pp = aL[b]*aR[b];
        float al = r*alpha[(long)b*SYNCN + k] + pp;
        alpha[(long)b*SYNCN + k] = al;
        syncb[(long)b*KPAD + k] = f2bf(al*rs);
    }
}

// bf16 MFMA split-K GEMM: part[sk][128][NPAD] = sync[128][KCH chunk] @ w_t^T
__global__ __launch_bounds__(256) void out_gemm_k(const unsigned short* __restrict__ Abf,
    const unsigned short* __restrict__ Bbf, float* __restrict__ part){
    int n_base = blockIdx.x*128;
    int sk = blockIdx.y;
    int tid = threadIdx.x;
    int wid = tid >> 6, lane = tid & 63;
    int wm = (wid & 1)*64, wn = (wid >> 1)*64;
    long k_base = (long)sk*KCH;
    __shared__ unsigned short As[128*40];
    __shared__ unsigned short Bs[128*40];
    f32x4 c[4][4];
#pragma unroll
    for (int a = 0; a < 4; ++a)
#pragma unroll
        for (int b = 0; b < 4; ++b) c[a][b] = (f32x4){0.f,0.f,0.f,0.f};

    int mrow = lane & 15, kq = lane >> 4;
    for (int ks = 0; ks < KCH/32; ++ks){
#pragma unroll
        for (int p = 0; p < 2; ++p){
            int i = tid*2 + p;
            int row = i >> 2, seg = i & 3;
            long koff = k_base + ks*32 + seg*8;
            uint4 va = *(const uint4*)(Abf + (long)row*KPAD + koff);
            *(uint4*)&As[row*40 + seg*8] = va;
            uint4 vb = *(const uint4*)(Bbf + (long)(n_base+row)*KPAD + koff);
            *(uint4*)&Bs[row*40 + seg*8] = vb;
        }
        __syncthreads();
        bf16x8 af[4], bf[4];
#pragma unroll
        for (int x = 0; x < 4; ++x){
            af[x] = *(const bf16x8*)&As[(wm + x*16 + mrow)*40 + kq*8];
            bf[x] = *(const bf16x8*)&Bs[(wn + x*16 + mrow)*40 + kq*8];
        }
#pragma unroll
        for (int a = 0; a < 4; ++a)
#pragma unroll
            for (int b = 0; b < 4; ++b)
                c[a][b] = __builtin_amdgcn_mfma_f32_16x16x32_bf16(af[a], bf[b], c[a][b], 0, 0, 0);
        __syncthreads();
    }
    float* outp = part + (long)sk*(128*NPAD);
#pragma unroll
    for (int a = 0; a < 4; ++a)
#pragma unroll
        for (int b = 0; b < 4; ++b){
            int r0 = wm + a*16 + (lane >> 4)*4;
            int col = n_base + wn + b*16 + (lane & 15);
#pragma unroll
            for (int reg = 0; reg < 4; ++reg)
                outp[(long)(r0+reg)*NPAD + col] = c[a][b][reg];
        }
}

// reduce split-K partials + bias, entropy; 1024 threads, 1 n per thread
__global__ __launch_bounds__(1024) void reduce_softmax_k(const float* __restrict__ part, const float* __restrict__ outb,
    float* __restrict__ pred_all, float* __restrict__ dout, int t){
    int b = blockIdx.x, tid = threadIdx.x;
    __shared__ float redA[16], redB[16];
    float v = -1e30f;
    if (tid < OUTD){
        float s = outb[tid];
        for (int sk = 0; sk < NSPLIT; ++sk) s += part[(long)sk*(128*NPAD) + (long)b*NPAD + tid];
        v = s;
    }
    float m = v;
#pragma unroll
    for (int off = 32; off; off >>= 1) m = fmaxf(m, __shfl_down(m, off));
    if ((tid & 63) == 0) redA[tid>>6] = m;
    __syncthreads();
    if (tid == 0){
        float r = redA[0];
        for (int i = 1; i < 16; ++i) r = fmaxf(r, redA[i]);
        redA[0] = r;
    }
    __syncthreads();
    float M = redA[0];
    __syncthreads();
    float e  = (tid < OUTD) ? __expf(v - M) : 0.f;
    float ev = e * ((tid < OUTD) ? v : 0.f);
    float z = e, s2 = ev;
#pragma unroll
    for (int off = 32; off; off >>= 1){
        z  += __shfl_down(z, off);
        s2 += __shfl_down(s2, off);
    }
    if ((tid & 63) == 0){ redA[tid>>6] = z; redB[tid>>6] = s2; }
    __syncthreads();
    if (tid == 0){
        float Z = 0.f, S = 0.f;
        for (int i = 0; i < 16; ++i){ Z += redA[i]; S += redB[i]; }
        float logZ = M + __logf(Z);
        float ne = (logZ - S/Z) / 6.907755278982137f;
        dout[PREDTOT + b*48 + t] = ne;
        dout[PREDTOT + b*48 + 24 + t] = 1.f - ne;
    }
    if (tid < OUTD) pred_all[(long)t*(BB*OUTD) + (long)b*OUTD + tid] = v;
}

// pred_all [t][b][n] -> d_out [b][n][t]
__global__ __launch_bounds__(256) void transpose_pred_k(const float* __restrict__ pa, float* __restrict__ dout){
    int b = blockIdx.x;
    int n0 = blockIdx.y*64;
    __shared__ float S[64][25];
    for (int i = threadIdx.x; i < 24*64; i += 256){
        int tt = i >> 6, j = i & 63;
        int n = n0 + j;
        if (n < OUTD) S[j][tt] = pa[(long)tt*(BB*OUTD) + (long)b*OUTD + n];
    }
    __syncthreads();
    for (int i = threadIdx.x; i < 64*24; i += 256){
        int j = i / 24, tt = i % 24;
        int n = n0 + j;
        if (n < OUTD) dout[(long)b*(OUTD*ITERS) + (long)n*ITERS + tt] = S[j][tt];
    }
}

// ---------------- host ----------------

extern "C" void kernel_launch(void* const* d_in, const int* in_sizes, int n_in,
                              void* d_out, int out_size, void* d_ws, size_t ws_size,
                              hipStream_t stream){
    const float* x      = (const float*)d_in[0];
    const float* syn_w  = (const float*)d_in[1];
    const float* syn_b  = (const float*)d_in[2];
    const float* ln_g   = (const float*)d_in[3];
    const float* ln_b   = (const float*)d_in[4];
    const float* tp_w1  = (const float*)d_in[5];
    const float* tp_b1  = (const float*)d_in[6];
    const float* tp_w2  = (const float*)d_in[7];
    const float* tp_b2  = (const float*)d_in[8];
    const float* sas    = (const float*)d_in[9];
    const float* strc   = (const float*)d_in[10];
    const float* decay  = (const float*)d_in[11];
    const float* out_w  = (const float*)d_in[12];
    const float* out_b  = (const float*)d_in[13];
    const int*   il     = (const int*)d_in[14];
    const int*   ir     = (const int*)d_in[15];
    float* dout = (float*)d_out;

    char* ws = (char*)d_ws;
    size_t off = 0;
    auto alloc = [&](size_t bytes)->void*{
        void* p = ws + off;
        off += (bytes + 255) & ~(size_t)255;
        return p;
    };
    unsigned short* trh = (unsigned short*)alloc((size_t)MEMN*DMODEL*BB*2);  // 13.1 MB [m][d][b]
    unsigned short* trl = (unsigned short*)alloc((size_t)MEMN*DMODEL*BB*2);  // 13.1 MB
    float* act     = (float*)alloc((size_t)DMODEL*BB*4);          // 1 MB     [d][b]
    float* C0      = (float*)alloc((size_t)BB*4096*4);            // 2.1 MB
    float* xt      = (float*)alloc((size_t)DIN*BB*4);             // 0.26 MB  [k][b]
    float* w2t     = (float*)alloc((size_t)DMODEL*64*4);          // 0.52 MB  [d][h*2+o]
    unsigned short* w1bf = (unsigned short*)alloc((size_t)DMODEL*5120*2);    // 21 MB [d][plane][h*40+m]
    float* alpha   = (float*)alloc((size_t)BB*SYNCN*4);           // 16.8 MB
    float* beta    = (float*)alloc((size_t)SYNCN*4);              // 0.13 MB
    unsigned short* syncb = (unsigned short*)alloc((size_t)BB*KPAD*2);   // 8.5 MB  [b][k]
    unsigned short* wbt   = (unsigned short*)alloc((size_t)NPAD*KPAD*2); // 68.2 MB [n][k]
    float* pred_all= (float*)alloc((size_t)ITERS*BB*OUTD*4);      // 12.3 MB
    // shared region: w1t (init, 13.1 MB) / zpart (8.4 MB) / part (27.3 MB) — disjoint lifetimes
    float* shared_big = (float*)alloc((size_t)NSPLIT*BB*NPAD*4);  // 27.3 MB
    float* w1t   = shared_big;
    float* zpart = shared_big;
    float* part  = shared_big;
    unsigned short* swT_h = (unsigned short*)alloc((size_t)4096*DMODEL*2); // 16.8 MB [n][k]
    unsigned short* swT_l = (unsigned short*)alloc((size_t)4096*DMODEL*2); // 16.8 MB
    unsigned short* aT_h  = (unsigned short*)alloc((size_t)BB*DMODEL*2);   // 0.52 MB [b][d]
    unsigned short* aT_l  = (unsigned short*)alloc((size_t)BB*DMODEL*2);   // 0.52 MB
    int* rowOf    = (int*)alloc((size_t)SYNCN*4);
    int* rowstart = (int*)alloc((size_t)NSY*4);
    (void)ws_size; (void)in_sizes; (void)n_in; (void)out_size;

    // ---- once-per-launch precompute ----
    init_trace_k<<<8192, 256, 0, stream>>>(strc, trh, trl);
    init_act_k<<<1024, 256, 0, stream>>>(sas, act);
    init_alpha_beta_k<<<256, 256, 0, stream>>>(sas, il, ir, alpha, beta);
    init_rowmap_k<<<256, 256, 0, stream>>>(rowOf, rowstart);
    transpose_f32_k<<<dim3(32, 25), 256, 0, stream>>>(tp_w1, w1t, 1600, 2048);
    w1bf_prep_k<<<2048, 256, 0, stream>>>(w1t, w1bf);
    transpose_f32_k<<<dim3(32, 1),  256, 0, stream>>>(tp_w2, w2t, 64, 2048);
    transpose_f32_k<<<dim3(8, 2),   256, 0, stream>>>(x, xt, 128, 512);
    wbf_transpose_k<<<dim3(520, 4), 256, 0, stream>>>(out_w, wbt);
    swt_convert_k<<<dim3(32, 16), 256, 0, stream>>>(syn_w, swT_h, swT_l);
    sync_pad_k<<<128, 256, 0, stream>>>(syncb);
    gemm_syn_k<<<64, 256, 0, stream>>>(xt, syn_w, syn_b, C0);
    act_convert_k<<<dim3(32, 2), 256, 0, stream>>>(act, aT_h, aT_l);

    // ---- 24 sequential iterations ----
    for (int t = 0; t < ITERS; ++t){
        syn_mfma_k<<<dim3(64, 4), 256, 0, stream>>>(aT_h, aT_l, swT_h, swT_l, zpart);
        glu_ln_k<<<128, 1024, 0, stream>>>(C0, zpart, ln_g, ln_b, trh, trl, t % MEMN);
        trace_proc_k<<<2048, 256, 0, stream>>>(trh, trl, w1bf, tp_b1, w2t, tp_b2, act, aT_h, aT_l, t);
        pairwise_sync_k<<<129, 256, 0, stream>>>(act, decay, il, ir, rowOf, rowstart, alpha, beta, syncb);
        out_gemm_k<<<dim3(8, NSPLIT), 256, 0, stream>>>(syncb, wbt, part);
        reduce_softmax_k<<<128, 1024, 0, stream>>>(part, out_b, pred_all, dout, t);
    }
    transpose_pred_k<<<dim3(128, 16), 256, 0, stream>>>(pred_all, dout);
}

// Round 4
// 2772.154 us; speedup vs baseline: 1.4451x; 1.1501x over previous
//
#include <hip/hip_runtime.h>
#include <stdint.h>

#define BB      128
#define DIN     512
#define DMODEL  2048
#define MEMN    25
#define NSY     256
#define OUTD    1000
#define ITERS   24
#define SYNCN   32896
#define KPAD    33792      // 32 splits * 1056 (33 k-steps of 32)
#define NPAD    1024
#define NSPLIT  32
#define KCH     1056
#define PREDTOT (BB*OUTD*ITERS)

typedef __attribute__((ext_vector_type(8))) short bf16x8;
typedef __attribute__((ext_vector_type(4))) float f32x4;

__device__ __forceinline__ unsigned short f2bf(float x){
    unsigned int u = __float_as_uint(x);
    u += 0x7fffu + ((u >> 16) & 1u);
    return (unsigned short)(u >> 16);
}
__device__ __forceinline__ float bf2f(unsigned short h){
    unsigned int u = ((unsigned int)h) << 16;
    return __uint_as_float(u);
}
__device__ __forceinline__ float sigm(float x){ return 1.f/(1.f + __expf(-x)); }

// ---------------- init kernels (run every launch: ws is re-poisoned) ----------------

// trace stored as bf16 hi/lo pair, layout [m][d][b] (b fastest)
__global__ __launch_bounds__(256) void init_trace_k(const float* __restrict__ st,
    unsigned short* __restrict__ trh, unsigned short* __restrict__ trl){
    const long N = (long)MEMN*DMODEL*BB;
    for (long i = (long)blockIdx.x*256 + threadIdx.x; i < N; i += (long)gridDim.x*256){
        int m = (int)(i / (DMODEL*BB));
        int rem = (int)(i % (DMODEL*BB));
        int d = rem >> 7;
        float v = st[d*MEMN + m];
        unsigned short h = f2bf(v);
        trh[i] = h;
        trl[i] = f2bf(v - bf2f(h));
    }
}

// act layout: [d][b]
__global__ __launch_bounds__(256) void init_act_k(const float* __restrict__ sas, float* __restrict__ act){
    for (int i = blockIdx.x*256 + threadIdx.x; i < DMODEL*BB; i += gridDim.x*256)
        act[i] = sas[i >> 7];
}

__global__ __launch_bounds__(256) void init_alpha_k(const float* __restrict__ sas,
    const int* __restrict__ il, const int* __restrict__ ir, float* __restrict__ alpha){
    int i = blockIdx.x, tid = threadIdx.x;
    if (tid >= NSY - i) return;
    int j = i + tid;
    int k = i*(2*NSY - i + 1)/2 + tid;
    float a0 = sas[il[i]] * sas[ir[j]];
    for (int b = 0; b < BB; ++b) alpha[b*SYNCN + k] = a0;
}

__global__ __launch_bounds__(256) void init_rowmap_k(int* __restrict__ rowOf, int* __restrict__ rowstart){
    int i = blockIdx.x, tid = threadIdx.x;
    int start = i*(2*NSY - i + 1)/2;
    int len = NSY - i;
    if (tid == 0) rowstart[i] = start;
    for (int t = tid; t < len; t += 256) rowOf[start + t] = i;
}

// generic f32 transpose: in[R][C] -> out[C][R]
__global__ __launch_bounds__(256) void transpose_f32_k(const float* __restrict__ in, float* __restrict__ out, int R, int C){
    __shared__ float S[64][65];
    int r0 = blockIdx.y*64, c0 = blockIdx.x*64;
    for (int i = threadIdx.x; i < 64*64; i += 256){
        int rr = i >> 6, cc = i & 63;
        int r = r0+rr, c = c0+cc;
        if (r < R && c < C) S[rr][cc] = in[(long)r*C + c];
    }
    __syncthreads();
    for (int i = threadIdx.x; i < 64*64; i += 256){
        int cc = i >> 6, rr = i & 63;
        int r = r0+rr, c = c0+cc;
        if (r < R && c < C) out[(long)c*R + r] = S[rr][cc];
    }
}

// w1t [d][m*64+h] f32 -> w1bf [d][plane(hi=0,lo=1)][h*40+m] bf16, m padded 25->40 with zeros
__global__ __launch_bounds__(256) void w1bf_prep_k(const float* __restrict__ w1t, unsigned short* __restrict__ w1bf){
    int d = blockIdx.x, tid = threadIdx.x;
    __shared__ float S[1600];
    for (int i = tid; i < 1600; i += 256) S[i] = w1t[(long)d*1600 + i];
    __syncthreads();
    for (int i = tid; i < 2560; i += 256){
        int h = i/40, m = i - h*40;
        float v = (m < MEMN) ? S[m*64 + h] : 0.f;
        unsigned short hi = f2bf(v);
        unsigned short lo = f2bf(v - bf2f(hi));
        w1bf[(long)d*5120 + i]        = hi;
        w1bf[(long)d*5120 + 2560 + i] = lo;
    }
}

// out_w f32 [SYNCN][OUTD] -> bf16 [NPAD][KPAD] (transposed); 64x64 tiles, 16.9KB LDS
__global__ __launch_bounds__(256) void wbf_transpose_k(const float* __restrict__ w, unsigned short* __restrict__ wt){
    __shared__ float S[64][65];
    int k0 = blockIdx.x*64, n0 = blockIdx.y*64;
    int tid = threadIdx.x;
    if (k0 >= SYNCN){
        // k-pad region: must be zero (syncb pad is zero; avoid NaN/inf garbage)
        uint4 z = {0u,0u,0u,0u};
#pragma unroll
        for (int p = 0; p < 2; ++p){
            int i = tid + p*256;          // 0..511, 8 ushorts each
            int nn = i >> 3, k8 = (i & 7)*8;
            *(uint4*)(wt + (long)(n0+nn)*KPAD + k0 + k8) = z;
        }
        return;
    }
    const long MAXI = (long)SYNCN*OUTD - 4;
#pragma unroll
    for (int p = 0; p < 4; ++p){
        int i = tid + p*256;
        int rr = i >> 4, c4 = (i & 15)*4;
        long idx = (long)(k0+rr)*OUTD + n0 + c4;
        if (idx > MAXI) idx = MAXI;       // clamp: avoids OOB read at the very end
        float4 v = *(const float4*)(w + idx);
        S[rr][c4+0]=v.x; S[rr][c4+1]=v.y; S[rr][c4+2]=v.z; S[rr][c4+3]=v.w;
    }
    __syncthreads();
#pragma unroll
    for (int p = 0; p < 4; ++p){
        int i = tid + p*256;
        int nn = i >> 4, k4 = (i & 15)*4;
        ushort4 o;
        o.x = f2bf(S[k4+0][nn]); o.y = f2bf(S[k4+1][nn]);
        o.z = f2bf(S[k4+2][nn]); o.w = f2bf(S[k4+3][nn]);
        *(ushort4*)(wt + (long)(n0+nn)*KPAD + k0 + k4) = o;
    }
}

// syn_w rows [512..2560) f32 [k][4096] -> swT hi/lo bf16 [n=4096][k=2048]; 64x64 tiles
__global__ __launch_bounds__(256) void swt_convert_k(const float* __restrict__ w,
    unsigned short* __restrict__ th, unsigned short* __restrict__ tl){
    __shared__ float S[64][65];
    int k0 = blockIdx.x*64, n0 = blockIdx.y*64;
    int tid = threadIdx.x;
#pragma unroll
    for (int p = 0; p < 4; ++p){
        int i = tid + p*256;
        int rr = i >> 4, c4 = (i & 15)*4;
        float4 v = *(const float4*)(w + (long)(512 + k0 + rr)*4096 + n0 + c4);
        S[rr][c4+0]=v.x; S[rr][c4+1]=v.y; S[rr][c4+2]=v.z; S[rr][c4+3]=v.w;
    }
    __syncthreads();
#pragma unroll
    for (int p = 0; p < 4; ++p){
        int i = tid + p*256;
        int nn = i >> 4, k4 = (i & 15)*4;
        ushort4 oh, ol;
        float v0 = S[k4+0][nn], v1 = S[k4+1][nn], v2 = S[k4+2][nn], v3 = S[k4+3][nn];
        oh.x = f2bf(v0); oh.y = f2bf(v1); oh.z = f2bf(v2); oh.w = f2bf(v3);
        ol.x = f2bf(v0 - bf2f(oh.x)); ol.y = f2bf(v1 - bf2f(oh.y));
        ol.z = f2bf(v2 - bf2f(oh.z)); ol.w = f2bf(v3 - bf2f(oh.w));
        *(ushort4*)(th + (long)(n0+nn)*DMODEL + k0 + k4) = oh;
        *(ushort4*)(tl + (long)(n0+nn)*DMODEL + k0 + k4) = ol;
    }
}

// act [d=2048][b=128] f32 -> aT hi/lo bf16 [b][d]  (init only; per-iter fused into trace_proc)
__global__ __launch_bounds__(256) void act_convert_k(const float* __restrict__ act,
    unsigned short* __restrict__ th, unsigned short* __restrict__ tl){
    __shared__ float S[64][65];
    int d0 = blockIdx.x*64, b0 = blockIdx.y*64;
    int tid = threadIdx.x;
#pragma unroll
    for (int p = 0; p < 4; ++p){
        int i = tid + p*256;
        int rr = i >> 4, c4 = (i & 15)*4;
        float4 v = *(const float4*)(act + (long)(d0+rr)*BB + b0 + c4);
        S[rr][c4+0]=v.x; S[rr][c4+1]=v.y; S[rr][c4+2]=v.z; S[rr][c4+3]=v.w;
    }
    __syncthreads();
#pragma unroll
    for (int p = 0; p < 4; ++p){
        int i = tid + p*256;
        int nn = i >> 4, k4 = (i & 15)*4;
        unsigned short h[4], l[4];
#pragma unroll
        for (int q = 0; q < 4; ++q){
            float v = S[k4+q][nn];
            h[q] = f2bf(v);
            l[q] = f2bf(v - bf2f(h[q]));
        }
        *(ushort4*)(th + (long)(b0+nn)*DMODEL + d0 + k4) = ushort4{h[0],h[1],h[2],h[3]};
        *(ushort4*)(tl + (long)(b0+nn)*DMODEL + d0 + k4) = ushort4{l[0],l[1],l[2],l[3]};
    }
}

// fp32 GEMM (once, for C0): out[b][j](4096) = bias + sum_k A[k][b]*Bw[k][j], K=512
__global__ __launch_bounds__(256) void gemm_syn_k(const float* __restrict__ A, const float* __restrict__ Bw,
    const float* __restrict__ bias, float* __restrict__ out){
    int j_base = blockIdx.x*64;
    int tid = threadIdx.x;
    __shared__ float As[16][128];
    __shared__ float Bs[16][68];
    int bg = tid & 15, jg = tid >> 4;
    int b0 = bg*8, j0 = jg*4;
    float acc[8][4];
#pragma unroll
    for (int i = 0; i < 8; ++i)
#pragma unroll
        for (int q = 0; q < 4; ++q) acc[i][q] = 0.f;
    for (int kt = 0; kt < 32; ++kt){
        {
            int i0 = tid*8;
            int kk = i0 >> 7, bb = i0 & 127;
            const float4* src = (const float4*)(A + (long)(kt*16+kk)*BB + bb);
            float4 v0 = src[0], v1 = src[1];
            *(float4*)&As[kk][bb]   = v0;
            *(float4*)&As[kk][bb+4] = v1;
        }
        {
            int i0 = tid*4;
            int kk = i0 >> 6, jj = i0 & 63;
            float4 v = *(const float4*)(Bw + (long)(kt*16+kk)*4096 + j_base + jj);
            *(float4*)&Bs[kk][jj] = v;
        }
        __syncthreads();
#pragma unroll
        for (int kk = 0; kk < 16; ++kk){
            float a[8], bv[4];
            *(float4*)&a[0] = *(float4*)&As[kk][b0];
            *(float4*)&a[4] = *(float4*)&As[kk][b0+4];
            *(float4*)&bv[0] = *(float4*)&Bs[kk][j0];
#pragma unroll
            for (int i = 0; i < 8; ++i)
#pragma unroll
                for (int q = 0; q < 4; ++q) acc[i][q] += a[i]*bv[q];
        }
        __syncthreads();
    }
#pragma unroll
    for (int i = 0; i < 8; ++i){
        int bb = b0 + i;
        float4 v;
        v.x = acc[i][0]+bias[j_base+j0+0]; v.y = acc[i][1]+bias[j_base+j0+1];
        v.z = acc[i][2]+bias[j_base+j0+2]; v.w = acc[i][3]+bias[j_base+j0+3];
        *(float4*)(out + (long)bb*4096 + j_base + j0) = v;
    }
}

// ---------------- per-iteration kernels ----------------

// bf16 hi/lo MFMA GEMM for syn: zpart[s][128][4096-slice] = actT @ swT^T, K=256 per split s (8 splits)
__global__ __launch_bounds__(256) void syn_mfma_k(const unsigned short* __restrict__ Ah, const unsigned short* __restrict__ Al,
    const unsigned short* __restrict__ Bh, const unsigned short* __restrict__ Bl, float* __restrict__ zpart){
    int nb = blockIdx.x;
    int s  = blockIdx.y;
    int tid = threadIdx.x;
    int wid = tid >> 6, lane = tid & 63;
    int wm = (wid & 1)*64, wn = (wid >> 1)*32;

    __shared__ unsigned short As_h[128*40], As_l[128*40], Bs_h[64*40], Bs_l[64*40];
    f32x4 c[4][2];
#pragma unroll
    for (int a = 0; a < 4; ++a)
#pragma unroll
        for (int b = 0; b < 2; ++b) c[a][b] = (f32x4){0.f,0.f,0.f,0.f};

    int mrow = lane & 15, kq = lane >> 4;
    for (int ks = 0; ks < 8; ++ks){
        long koff_base = (long)s*256 + ks*32;
#pragma unroll
        for (int p = 0; p < 2; ++p){
            int idx = tid*2 + p;
            int row = idx >> 2, seg = idx & 3;
            long koff = koff_base + seg*8;
            *(uint4*)&As_h[row*40 + seg*8] = *(const uint4*)(Ah + (long)row*DMODEL + koff);
            *(uint4*)&As_l[row*40 + seg*8] = *(const uint4*)(Al + (long)row*DMODEL + koff);
        }
        {
            int row = tid >> 2, seg = tid & 3;
            long koff = koff_base + seg*8;
            *(uint4*)&Bs_h[row*40 + seg*8] = *(const uint4*)(Bh + (long)(nb*64+row)*DMODEL + koff);
            *(uint4*)&Bs_l[row*40 + seg*8] = *(const uint4*)(Bl + (long)(nb*64+row)*DMODEL + koff);
        }
        __syncthreads();
        bf16x8 ah[4], al[4], bh[2], bl[2];
#pragma unroll
        for (int x = 0; x < 4; ++x){
            ah[x] = *(const bf16x8*)&As_h[(wm + x*16 + mrow)*40 + kq*8];
            al[x] = *(const bf16x8*)&As_l[(wm + x*16 + mrow)*40 + kq*8];
        }
#pragma unroll
        for (int y = 0; y < 2; ++y){
            bh[y] = *(const bf16x8*)&Bs_h[(wn + y*16 + mrow)*40 + kq*8];
            bl[y] = *(const bf16x8*)&Bs_l[(wn + y*16 + mrow)*40 + kq*8];
        }
#pragma unroll
        for (int a = 0; a < 4; ++a)
#pragma unroll
            for (int b = 0; b < 2; ++b){
                c[a][b] = __builtin_amdgcn_mfma_f32_16x16x32_bf16(ah[a], bh[b], c[a][b], 0, 0, 0);
                c[a][b] = __builtin_amdgcn_mfma_f32_16x16x32_bf16(al[a], bh[b], c[a][b], 0, 0, 0);
                c[a][b] = __builtin_amdgcn_mfma_f32_16x16x32_bf16(ah[a], bl[b], c[a][b], 0, 0, 0);
            }
        __syncthreads();
    }
    float* outp = zpart + (long)s*(BB*4096);
#pragma unroll
    for (int a = 0; a < 4; ++a)
#pragma unroll
        for (int b = 0; b < 2; ++b){
            int r0 = wm + a*16 + (lane >> 4)*4;
            int col = nb*64 + wn + b*16 + (lane & 15);
#pragma unroll
            for (int reg = 0; reg < 4; ++reg)
                outp[(long)(r0+reg)*4096 + col] = c[a][b][reg];
        }
}

// GLU + LayerNorm, 1024 threads; z = C0 + sum of 8 zpart splits; writes bf16 hi/lo trace slot
__global__ __launch_bounds__(1024) void glu_ln_k(const float* __restrict__ C0, const float* __restrict__ zp,
    const float* __restrict__ lng, const float* __restrict__ lnb,
    unsigned short* __restrict__ trh, unsigned short* __restrict__ trl, int slot){
    int b = blockIdx.x, tid = threadIdx.x;
    __shared__ float redA[16], redB[16];
    int d0 = tid*2;
    const float* base = C0 + (long)b*4096;
    float2 a = *(const float2*)(base + d0);
    float2 g = *(const float2*)(base + 2048 + d0);
#pragma unroll
    for (int s = 0; s < 8; ++s){
        const float* zb = zp + (long)s*524288 + (long)b*4096;
        float2 az = *(const float2*)(zb + d0);
        float2 gz = *(const float2*)(zb + 2048 + d0);
        a.x += az.x; a.y += az.y; g.x += gz.x; g.y += gz.y;
    }
    float v0 = a.x*sigm(g.x), v1 = a.y*sigm(g.y);
    float s1 = v0+v1, s2 = v0*v0+v1*v1;
#pragma unroll
    for (int off = 32; off; off >>= 1){
        s1 += __shfl_down(s1, off);
        s2 += __shfl_down(s2, off);
    }
    if ((tid & 63) == 0){ redA[tid>>6] = s1; redB[tid>>6] = s2; }
    __syncthreads();
    if (tid == 0){
        float sa = 0.f, sb = 0.f;
        for (int i = 0; i < 16; ++i){ sa += redA[i]; sb += redB[i]; }
        float mu = sa*(1.f/2048.f);
        float var = sb*(1.f/2048.f) - mu*mu;
        redA[0] = mu;
        redB[0] = rsqrtf(var + 1e-5f);
    }
    __syncthreads();
    float mu = redA[0], inv = redB[0];
    float st0 = (v0-mu)*inv*lng[d0]   + lnb[d0];
    float st1 = (v1-mu)*inv*lng[d0+1] + lnb[d0+1];
    unsigned short h0 = f2bf(st0), h1 = f2bf(st1);
    long o0 = ((long)slot*DMODEL + d0)*BB + b;
    trh[o0]      = h0;  trl[o0]      = f2bf(st0 - bf2f(h0));
    trh[o0 + BB] = h1;  trl[o0 + BB] = f2bf(st1 - bf2f(h1));
}

// trace_proc via bf16 hi/lo MFMA. Per-d block. Epilogue fuses act write + aT hi/lo convert.
__global__ __launch_bounds__(256) void trace_proc_k(
    const unsigned short* __restrict__ trh, const unsigned short* __restrict__ trl,
    const unsigned short* __restrict__ w1bf,
    const float* __restrict__ b1, const float* __restrict__ w2t, const float* __restrict__ b2,
    float* __restrict__ act, unsigned short* __restrict__ aTh, unsigned short* __restrict__ aTl, int t){
    int d = blockIdx.x, tid = threadIdx.x;
    __shared__ __align__(16) unsigned short Ah[128*40];
    __shared__ __align__(16) unsigned short Al[128*40];
    __shared__ __align__(16) unsigned short Bbuf[5120];
    __shared__ float hh[128*33];
    __shared__ float w2s[64];

    for (int i = tid; i < MEMN*64; i += 256){
        int m = i >> 6, bp = i & 63;
        int phys = t + 1 + m; if (phys >= MEMN) phys -= MEMN; if (phys >= MEMN) phys -= MEMN;
        long gaddr = ((long)phys*DMODEL + d)*BB + bp*2;
        ushort2 vh = *(const ushort2*)(trh + gaddr);
        ushort2 vl = *(const ushort2*)(trl + gaddr);
        Ah[(bp*2+0)*40 + m] = vh.x; Ah[(bp*2+1)*40 + m] = vh.y;
        Al[(bp*2+0)*40 + m] = vl.x; Al[(bp*2+1)*40 + m] = vl.y;
    }
    for (int i = tid; i < 7*128; i += 256){
        int m = MEMN + (i >> 7), b = i & 127;
        Ah[b*40 + m] = 0; Al[b*40 + m] = 0;
    }
    {
        const uint4* src = (const uint4*)(w1bf + (long)d*5120);
        uint4* dst = (uint4*)Bbuf;
        for (int i = tid; i < 640; i += 256) dst[i] = src[i];
    }
    if (tid < 64) w2s[tid] = w2t[(long)d*64 + tid];
    __syncthreads();

    int wid = tid >> 6, lane = tid & 63;
    int mrow = lane & 15, kq = lane >> 4;
    bf16x8 ahf[2], alf[2], bhf[4], blf[4];
#pragma unroll
    for (int bt = 0; bt < 2; ++bt){
        int r = (wid*2 + bt)*16 + mrow;
        ahf[bt] = *(const bf16x8*)&Ah[r*40 + kq*8];
        alf[bt] = *(const bf16x8*)&Al[r*40 + kq*8];
    }
#pragma unroll
    for (int ht = 0; ht < 4; ++ht){
        int r = ht*16 + mrow;
        bhf[ht] = *(const bf16x8*)&Bbuf[r*40 + kq*8];
        blf[ht] = *(const bf16x8*)&Bbuf[2560 + r*40 + kq*8];
    }
    f32x4 c[2][4];
#pragma unroll
    for (int bt = 0; bt < 2; ++bt)
#pragma unroll
        for (int ht = 0; ht < 4; ++ht){
            c[bt][ht] = (f32x4){0.f,0.f,0.f,0.f};
            c[bt][ht] = __builtin_amdgcn_mfma_f32_16x16x32_bf16(ahf[bt], bhf[ht], c[bt][ht], 0, 0, 0);
            c[bt][ht] = __builtin_amdgcn_mfma_f32_16x16x32_bf16(alf[bt], bhf[ht], c[bt][ht], 0, 0, 0);
            c[bt][ht] = __builtin_amdgcn_mfma_f32_16x16x32_bf16(ahf[bt], blf[ht], c[bt][ht], 0, 0, 0);
        }
    int quad = lane >> 4;
#pragma unroll
    for (int bt = 0; bt < 2; ++bt){
        int bb0 = (wid*2 + bt)*16 + quad*4;
#pragma unroll
        for (int ht = 0; ht < 2; ++ht){
            int h = ht*16 + (lane & 15);
            float ba = b1[(long)d*64 + h];
            float bg = b1[(long)d*64 + 32 + h];
#pragma unroll
            for (int reg = 0; reg < 4; ++reg){
                float a = c[bt][ht][reg] + ba;
                float g = c[bt][ht+2][reg] + bg;
                hh[(bb0+reg)*33 + h] = a * sigm(g);
            }
        }
    }
    __syncthreads();
    if (tid < 128){
        int bb = tid;
        float o0 = b2[(long)d*2+0], o1 = b2[(long)d*2+1];
#pragma unroll
        for (int h = 0; h < 32; ++h){
            float hv = hh[bb*33 + h];
            o0 += hv * w2s[h*2+0];
            o1 += hv * w2s[h*2+1];
        }
        float a = o0 * sigm(o1);
        act[(long)d*BB + bb] = a;
        unsigned short h16 = f2bf(a);
        aTh[(long)bb*DMODEL + d] = h16;
        aTl[(long)bb*DMODEL + d] = f2bf(a - bf2f(h16));
    }
}

// pairwise + alpha update + sync write. Grid (KPAD/256, 4): 4-way batch split, closed-form beta.
__global__ __launch_bounds__(256) void pairwise_sync_k(const float* __restrict__ act, const float* __restrict__ decay,
    const int* __restrict__ il, const int* __restrict__ ir,
    const int* __restrict__ rowOf, const int* __restrict__ rowstart,
    float* __restrict__ alpha, unsigned short* __restrict__ syncb, int t){
    int k = blockIdx.x*256 + threadIdx.x;
    int bg = blockIdx.y;
    int blo = bg*32, bhi = blo + 32;
    if (k >= SYNCN){
        if (k < KPAD)
            for (int b = blo; b < bhi; ++b) syncb[(long)b*KPAD + k] = 0;
        return;
    }
    int i = rowOf[k];
    int j = i + (k - rowstart[i]);
    float cc = fminf(fmaxf(decay[k], 0.f), 15.f);
    float r = __expf(-cc);
    // beta_t = r^{t+1} + (1 - r^{t+1})/(1 - r)  (exact closed form of the recurrence)
    float bet;
    if (cc < 1e-30f) bet = (float)(t + 2);
    else {
        float e1 = expm1f(-cc);
        float et = expm1f(-cc*(float)(t+1));
        bet = 1.f + et + et/e1;
    }
    float rs = rsqrtf(bet);
    const float* aL = act + (long)il[i]*BB;
    const float* aR = act + (long)ir[j]*BB;
    for (int b = blo; b < bhi; ++b){
        float pp = aL[b]*aR[b];
        float al = r*alpha[(long)b*SYNCN + k] + pp;
        alpha[(long)b*SYNCN + k] = al;
        syncb[(long)b*KPAD + k] = f2bf(al*rs);
    }
}

// bf16 MFMA split-K GEMM: part[sk][128][NPAD] = sync[128][KCH chunk] @ wt^T; tile M128 x N64
__global__ __launch_bounds__(256) void out_gemm_k(const unsigned short* __restrict__ Abf,
    const unsigned short* __restrict__ Bbf, float* __restrict__ part){
    int n_base = blockIdx.x*64;
    int sk = blockIdx.y;
    int tid = threadIdx.x;
    int wid = tid >> 6, lane = tid & 63;
    int wm = (wid & 1)*64, wn = (wid >> 1)*32;
    long k_base = (long)sk*KCH;
    __shared__ unsigned short As[128*40];
    __shared__ unsigned short Bs[64*40];
    f32x4 c[4][2];
#pragma unroll
    for (int a = 0; a < 4; ++a)
#pragma unroll
        for (int b = 0; b < 2; ++b) c[a][b] = (f32x4){0.f,0.f,0.f,0.f};

    int mrow = lane & 15, kq = lane >> 4;
    for (int ks = 0; ks < KCH/32; ++ks){
#pragma unroll
        for (int p = 0; p < 2; ++p){
            int i = tid*2 + p;
            int row = i >> 2, seg = i & 3;
            long koff = k_base + ks*32 + seg*8;
            *(uint4*)&As[row*40 + seg*8] = *(const uint4*)(Abf + (long)row*KPAD + koff);
        }
        {
            int row = tid >> 2, seg = tid & 3;
            long koff = k_base + ks*32 + seg*8;
            *(uint4*)&Bs[row*40 + seg*8] = *(const uint4*)(Bbf + (long)(n_base+row)*KPAD + koff);
        }
        __syncthreads();
        bf16x8 af[4], bf[2];
#pragma unroll
        for (int x = 0; x < 4; ++x)
            af[x] = *(const bf16x8*)&As[(wm + x*16 + mrow)*40 + kq*8];
#pragma unroll
        for (int y = 0; y < 2; ++y)
            bf[y] = *(const bf16x8*)&Bs[(wn + y*16 + mrow)*40 + kq*8];
#pragma unroll
        for (int a = 0; a < 4; ++a)
#pragma unroll
            for (int b = 0; b < 2; ++b)
                c[a][b] = __builtin_amdgcn_mfma_f32_16x16x32_bf16(af[a], bf[b], c[a][b], 0, 0, 0);
        __syncthreads();
    }
    float* outp = part + (long)sk*(128*NPAD);
#pragma unroll
    for (int a = 0; a < 4; ++a)
#pragma unroll
        for (int b = 0; b < 2; ++b){
            int r0 = wm + a*16 + (lane >> 4)*4;
            int col = n_base + wn + b*16 + (lane & 15);
#pragma unroll
            for (int reg = 0; reg < 4; ++reg)
                outp[(long)(r0+reg)*NPAD + col] = c[a][b][reg];
        }
}

// reduce split-K partials + bias, entropy; 1024 threads, 1 n per thread
__global__ __launch_bounds__(1024) void reduce_softmax_k(const float* __restrict__ part, const float* __restrict__ outb,
    float* __restrict__ pred_all, float* __restrict__ dout, int t){
    int b = blockIdx.x, tid = threadIdx.x;
    __shared__ float redA[16], redB[16];
    float v = -1e30f;
    if (tid < OUTD){
        float s = outb[tid];
        for (int sk = 0; sk < NSPLIT; ++sk) s += part[(long)sk*(128*NPAD) + (long)b*NPAD + tid];
        v = s;
    }
    float m = v;
#pragma unroll
    for (int off = 32; off; off >>= 1) m = fmaxf(m, __shfl_down(m, off));
    if ((tid & 63) == 0) redA[tid>>6] = m;
    __syncthreads();
    if (tid == 0){
        float r = redA[0];
        for (int i = 1; i < 16; ++i) r = fmaxf(r, redA[i]);
        redA[0] = r;
    }
    __syncthreads();
    float M = redA[0];
    __syncthreads();
    float e  = (tid < OUTD) ? __expf(v - M) : 0.f;
    float ev = e * ((tid < OUTD) ? v : 0.f);
    float z = e, s2 = ev;
#pragma unroll
    for (int off = 32; off; off >>= 1){
        z  += __shfl_down(z, off);
        s2 += __shfl_down(s2, off);
    }
    if ((tid & 63) == 0){ redA[tid>>6] = z; redB[tid>>6] = s2; }
    __syncthreads();
    if (tid == 0){
        float Z = 0.f, S = 0.f;
        for (int i = 0; i < 16; ++i){ Z += redA[i]; S += redB[i]; }
        float logZ = M + __logf(Z);
        float ne = (logZ - S/Z) / 6.907755278982137f;
        dout[PREDTOT + b*48 + t] = ne;
        dout[PREDTOT + b*48 + 24 + t] = 1.f - ne;
    }
    if (tid < OUTD) pred_all[(long)t*(BB*OUTD) + (long)b*OUTD + tid] = v;
}

// pred_all [t][b][n] -> d_out [b][n][t]
__global__ __launch_bounds__(256) void transpose_pred_k(const float* __restrict__ pa, float* __restrict__ dout){
    int b = blockIdx.x;
    int n0 = blockIdx.y*64;
    __shared__ float S[64][25];
    for (int i = threadIdx.x; i < 24*64; i += 256){
        int tt = i >> 6, j = i & 63;
        int n = n0 + j;
        if (n < OUTD) S[j][tt] = pa[(long)tt*(BB*OUTD) + (long)b*OUTD + n];
    }
    __syncthreads();
    for (int i = threadIdx.x; i < 64*24; i += 256){
        int j = i / 24, tt = i % 24;
        int n = n0 + j;
        if (n < OUTD) dout[(long)b*(OUTD*ITERS) + (long)n*ITERS + tt] = S[j][tt];
    }
}

// ---------------- host ----------------

extern "C" void kernel_launch(void* const* d_in, const int* in_sizes, int n_in,
                              void* d_out, int out_size, void* d_ws, size_t ws_size,
                              hipStream_t stream){
    const float* x      = (const float*)d_in[0];
    const float* syn_w  = (const float*)d_in[1];
    const float* syn_b  = (const float*)d_in[2];
    const float* ln_g   = (const float*)d_in[3];
    const float* ln_b   = (const float*)d_in[4];
    const float* tp_w1  = (const float*)d_in[5];
    const float* tp_b1  = (const float*)d_in[6];
    const float* tp_w2  = (const float*)d_in[7];
    const float* tp_b2  = (const float*)d_in[8];
    const float* sas    = (const float*)d_in[9];
    const float* strc   = (const float*)d_in[10];
    const float* decay  = (const float*)d_in[11];
    const float* out_w  = (const float*)d_in[12];
    const float* out_b  = (const float*)d_in[13];
    const int*   il     = (const int*)d_in[14];
    const int*   ir     = (const int*)d_in[15];
    float* dout = (float*)d_out;

    char* ws = (char*)d_ws;
    size_t off = 0;
    auto alloc = [&](size_t bytes)->void*{
        void* p = ws + off;
        off += (bytes + 255) & ~(size_t)255;
        return p;
    };
    unsigned short* trh = (unsigned short*)alloc((size_t)MEMN*DMODEL*BB*2);  // 13.1 MB [m][d][b]
    unsigned short* trl = (unsigned short*)alloc((size_t)MEMN*DMODEL*BB*2);  // 13.1 MB
    float* act     = (float*)alloc((size_t)DMODEL*BB*4);          // 1 MB     [d][b]
    float* C0      = (float*)alloc((size_t)BB*4096*4);            // 2.1 MB
    float* xt      = (float*)alloc((size_t)DIN*BB*4);             // 0.26 MB  [k][b]
    float* w2t     = (float*)alloc((size_t)DMODEL*64*4);          // 0.52 MB  [d][h*2+o]
    unsigned short* w1bf = (unsigned short*)alloc((size_t)DMODEL*5120*2);    // 21 MB [d][plane][h*40+m]
    float* alpha   = (float*)alloc((size_t)BB*SYNCN*4);           // 16.8 MB
    unsigned short* syncb = (unsigned short*)alloc((size_t)BB*KPAD*2);   // 8.65 MB [b][k]
    unsigned short* wbt   = (unsigned short*)alloc((size_t)NPAD*KPAD*2); // 69.2 MB [n][k]
    float* pred_all= (float*)alloc((size_t)ITERS*BB*OUTD*4);      // 12.3 MB
    // shared region: w1t (init) / zpart (8 splits, 16.8 MB) / part (32 splits, 16.8 MB)
    float* shared_big = (float*)alloc((size_t)NSPLIT*BB*NPAD*4);  // 16.8 MB
    float* w1t   = shared_big;
    float* zpart = shared_big;
    float* part  = shared_big;
    unsigned short* swT_h = (unsigned short*)alloc((size_t)4096*DMODEL*2); // 16.8 MB [n][k]
    unsigned short* swT_l = (unsigned short*)alloc((size_t)4096*DMODEL*2); // 16.8 MB
    unsigned short* aT_h  = (unsigned short*)alloc((size_t)BB*DMODEL*2);   // 0.52 MB [b][d]
    unsigned short* aT_l  = (unsigned short*)alloc((size_t)BB*DMODEL*2);   // 0.52 MB
    int* rowOf    = (int*)alloc((size_t)SYNCN*4);
    int* rowstart = (int*)alloc((size_t)NSY*4);
    (void)ws_size; (void)in_sizes; (void)n_in; (void)out_size;

    // ---- once-per-launch precompute ----
    init_trace_k<<<8192, 256, 0, stream>>>(strc, trh, trl);
    init_act_k<<<1024, 256, 0, stream>>>(sas, act);
    init_alpha_k<<<256, 256, 0, stream>>>(sas, il, ir, alpha);
    init_rowmap_k<<<256, 256, 0, stream>>>(rowOf, rowstart);
    transpose_f32_k<<<dim3(32, 25), 256, 0, stream>>>(tp_w1, w1t, 1600, 2048);
    w1bf_prep_k<<<2048, 256, 0, stream>>>(w1t, w1bf);
    transpose_f32_k<<<dim3(32, 1),  256, 0, stream>>>(tp_w2, w2t, 64, 2048);
    transpose_f32_k<<<dim3(8, 2),   256, 0, stream>>>(x, xt, 128, 512);
    wbf_transpose_k<<<dim3(KPAD/64, 16), 256, 0, stream>>>(out_w, wbt);
    swt_convert_k<<<dim3(32, 64), 256, 0, stream>>>(syn_w, swT_h, swT_l);
    gemm_syn_k<<<64, 256, 0, stream>>>(xt, syn_w, syn_b, C0);
    act_convert_k<<<dim3(32, 2), 256, 0, stream>>>(act, aT_h, aT_l);

    // ---- 24 sequential iterations ----
    for (int t = 0; t < ITERS; ++t){
        syn_mfma_k<<<dim3(64, 8), 256, 0, stream>>>(aT_h, aT_l, swT_h, swT_l, zpart);
        glu_ln_k<<<128, 1024, 0, stream>>>(C0, zpart, ln_g, ln_b, trh, trl, t % MEMN);
        trace_proc_k<<<2048, 256, 0, stream>>>(trh, trl, w1bf, tp_b1, w2t, tp_b2, act, aT_h, aT_l, t);
        pairwise_sync_k<<<dim3(KPAD/256, 4), 256, 0, stream>>>(act, decay, il, ir, rowOf, rowstart, alpha, syncb, t);
        out_gemm_k<<<dim3(16, NSPLIT), 256, 0, stream>>>(syncb, wbt, part);
        reduce_softmax_k<<<128, 1024, 0, stream>>>(part, out_b, pred_all, dout, t);
    }
    transpose_pred_k<<<dim3(128, 16), 256, 0, stream>>>(pred_all, dout);
}